// Round 1
// baseline (993.303 us; speedup 1.0000x reference)
//
#include <hip/hip_runtime.h>
#include <math.h>

#define B_   16
#define SQ_  1024
#define SC_  1024
#define D_   768
#define H_   1536

// ---------------------------------------------------------------------------
// Kernel 1: S[b,i,j] = dot(q[b,i,:], c[b,j,:]) with mask semantics:
//   s = dot * mq * mc; s = (s == 0) ? -inf : s
// 64x64 tile per 256-thread block, 4x4 micro-tile per thread, K-chunk 16.
// ---------------------------------------------------------------------------
__global__ __launch_bounds__(256) void gemm_mask_kernel(
    const float* __restrict__ q, const float* __restrict__ c,
    const int* __restrict__ mask_q, const int* __restrict__ mask_c,
    float* __restrict__ S)
{
  int b  = blockIdx.z;
  int i0 = blockIdx.y * 64;
  int j0 = blockIdx.x * 64;

  __shared__ float As[16][64];
  __shared__ float Bs[16][64];

  int t    = threadIdx.x;
  int lrow = t >> 2;          // 0..63  (tile row this thread loads)
  int lk4  = (t & 3) << 2;    // 0,4,8,12 (k sub-offset, float4)
  int ty   = t >> 4;          // 0..15
  int tx   = t & 15;          // 0..15

  const float* qb = q + ((size_t)b * SQ_ + i0) * D_;
  const float* cb = c + ((size_t)b * SC_ + j0) * D_;

  float acc[4][4];
#pragma unroll
  for (int r = 0; r < 4; ++r)
#pragma unroll
    for (int cc = 0; cc < 4; ++cc) acc[r][cc] = 0.f;

  for (int k0 = 0; k0 < D_; k0 += 16) {
    float4 av = *(const float4*)(qb + (size_t)lrow * D_ + k0 + lk4);
    float4 bv = *(const float4*)(cb + (size_t)lrow * D_ + k0 + lk4);
    __syncthreads();
    As[lk4 + 0][lrow] = av.x; As[lk4 + 1][lrow] = av.y;
    As[lk4 + 2][lrow] = av.z; As[lk4 + 3][lrow] = av.w;
    Bs[lk4 + 0][lrow] = bv.x; Bs[lk4 + 1][lrow] = bv.y;
    Bs[lk4 + 2][lrow] = bv.z; Bs[lk4 + 3][lrow] = bv.w;
    __syncthreads();
#pragma unroll
    for (int kk = 0; kk < 16; ++kk) {
      float4 a4 = *(const float4*)&As[kk][ty * 4];
      float4 b4 = *(const float4*)&Bs[kk][tx * 4];
      float ar[4] = {a4.x, a4.y, a4.z, a4.w};
      float br[4] = {b4.x, b4.y, b4.z, b4.w};
#pragma unroll
      for (int r = 0; r < 4; ++r)
#pragma unroll
        for (int cc = 0; cc < 4; ++cc) acc[r][cc] += ar[r] * br[cc];
    }
  }

#pragma unroll
  for (int r = 0; r < 4; ++r) {
    int i   = i0 + ty * 4 + r;
    int mqv = mask_q[b * SQ_ + i];
    float4 outv;
    float vals[4];
#pragma unroll
    for (int cc = 0; cc < 4; ++cc) {
      int j   = j0 + tx * 4 + cc;
      int mcv = mask_c[b * SC_ + j];
      float s = acc[r][cc];
      bool valid = (mqv != 0) && (mcv != 0) && (s != 0.0f);
      vals[cc] = valid ? s : -INFINITY;
    }
    outv.x = vals[0]; outv.y = vals[1]; outv.z = vals[2]; outv.w = vals[3];
    *(float4*)&S[((size_t)b * SQ_ + i) * SC_ + j0 + tx * 4] = outv;
  }
}

// ---------------------------------------------------------------------------
// Kernel 2: per-row (over j) max and sum(exp(s-max)).  One wave per row.
// ---------------------------------------------------------------------------
__global__ __launch_bounds__(256) void row_stats_kernel(
    const float* __restrict__ S, float* __restrict__ rowmax, float* __restrict__ rowsum)
{
  int w    = threadIdx.x >> 6;
  int lane = threadIdx.x & 63;
  int rowIdx = blockIdx.x * 4 + w;       // b*SQ_ + i
  const float* Srow = S + (size_t)rowIdx * SC_;

  float m = -INFINITY;
  for (int j = lane; j < SC_; j += 64) m = fmaxf(m, Srow[j]);
#pragma unroll
  for (int o = 32; o; o >>= 1) m = fmaxf(m, __shfl_xor(m, o));

  float ssum = 0.f;
  if (m > -INFINITY) {
    for (int j = lane; j < SC_; j += 64) ssum += expf(Srow[j] - m);
  }
#pragma unroll
  for (int o = 32; o; o >>= 1) ssum += __shfl_xor(ssum, o);

  if (lane == 0) { rowmax[rowIdx] = m; rowsum[rowIdx] = ssum; }
}

// ---------------------------------------------------------------------------
// Kernel 3: per-column (over i) max and sum(exp(s-max)). Thread per column.
// ---------------------------------------------------------------------------
__global__ __launch_bounds__(256) void col_stats_kernel(
    const float* __restrict__ S, float* __restrict__ colmax, float* __restrict__ colsum)
{
  int b = blockIdx.y;
  int j = blockIdx.x * 256 + threadIdx.x;
  const float* Sb = S + (size_t)b * SQ_ * SC_;

  float m = -INFINITY;
  for (int i = 0; i < SQ_; ++i) m = fmaxf(m, Sb[(size_t)i * SC_ + j]);
  float ssum = 0.f;
  if (m > -INFINITY) {
    for (int i = 0; i < SQ_; ++i) ssum += expf(Sb[(size_t)i * SC_ + j] - m);
  }
  colmax[b * SC_ + j] = m;
  colsum[b * SC_ + j] = ssum;
}

// ---------------------------------------------------------------------------
// Kernel 4: colsum_p[b,j] = sum_i exp(S[b,i,j]-rowmax[b,i]) / rowsum[b,i]
// ---------------------------------------------------------------------------
__global__ __launch_bounds__(256) void colsum_p_kernel(
    const float* __restrict__ S, const float* __restrict__ rowmax,
    const float* __restrict__ rowsum, float* __restrict__ colsum_p)
{
  int b = blockIdx.y;
  int j = blockIdx.x * 256 + threadIdx.x;
  const float* Sb = S + (size_t)b * SQ_ * SC_;
  const float* rm = rowmax + b * SQ_;
  const float* rs = rowsum + b * SQ_;

  float accv = 0.f;
  for (int i = 0; i < SQ_; ++i) {
    float m = rm[i];
    if (m > -INFINITY) {
      float inv = 1.0f / rs[i];
      accv += expf(Sb[(size_t)i * SC_ + j] - m) * inv;
    }
  }
  colsum_p[b * SC_ + j] = accv;
}

// ---------------------------------------------------------------------------
// Kernel 5: rowsum_pp[b,i] = sum_j exp(S[b,i,j]-colmax[b,j]) / colsum[b,j]
// ---------------------------------------------------------------------------
__global__ __launch_bounds__(256) void rowsum_pp_kernel(
    const float* __restrict__ S, const float* __restrict__ colmax,
    const float* __restrict__ colsum, float* __restrict__ rowsum_pp)
{
  int w    = threadIdx.x >> 6;
  int lane = threadIdx.x & 63;
  int rowIdx = blockIdx.x * 4 + w;   // b*SQ_ + i
  int b = rowIdx >> 10;
  const float* Srow = S + (size_t)rowIdx * SC_;
  const float* cm = colmax + b * SC_;
  const float* cs = colsum + b * SC_;

  float accv = 0.f;
  for (int j = lane; j < SC_; j += 64) {
    float m = cm[j];
    if (m > -INFINITY) accv += expf(Srow[j] - m) / cs[j];
  }
#pragma unroll
  for (int o = 32; o; o >>= 1) accv += __shfl_xor(accv, o);
  if (lane == 0) rowsum_pp[rowIdx] = accv;
}

// ---------------------------------------------------------------------------
// Kernel 6: a[b,k] = sum_j colsum_p[b,j]*c[b,j,k] ; bb[b,k] = sum_i rowsum_pp[b,i]*q[b,i,k]
// X[b, 0:768] = a ; X[b, 768:1536] = bb
// ---------------------------------------------------------------------------
__global__ __launch_bounds__(256) void combine_kernel(
    const float* __restrict__ q, const float* __restrict__ c,
    const float* __restrict__ colsum_p, const float* __restrict__ rowsum_pp,
    float* __restrict__ X)
{
  int b    = blockIdx.y;
  int part = blockIdx.x;   // 0..5
  int t    = threadIdx.x;

  if (part < 3) {
    int k = part * 256 + t;
    const float* cb = c + (size_t)b * SC_ * D_;
    const float* wv = colsum_p + b * SC_;
    float accv = 0.f;
    for (int j = 0; j < SC_; ++j) accv += wv[j] * cb[(size_t)j * D_ + k];
    X[b * H_ + k] = accv;
  } else {
    int k = (part - 3) * 256 + t;
    const float* qb = q + (size_t)b * SQ_ * D_;
    const float* wv = rowsum_pp + b * SQ_;
    float accv = 0.f;
    for (int i = 0; i < SQ_; ++i) accv += wv[i] * qb[(size_t)i * D_ + k];
    X[b * H_ + D_ + k] = accv;
  }
}

// ---------------------------------------------------------------------------
// Kernel 7: Y[b,h] = tanh(X[b,:] . W1[h,:] + b1[h])
// ---------------------------------------------------------------------------
__global__ __launch_bounds__(256) void fc1_kernel(
    const float* __restrict__ X, const float* __restrict__ W1,
    const float* __restrict__ b1, float* __restrict__ Y)
{
  int idx = blockIdx.x * 256 + threadIdx.x;   // 0..16*1536-1
  int b = idx & 15;
  int h = idx >> 4;
  const float* x = X + b * H_;
  const float* w = W1 + (size_t)h * H_;
  float accv = b1[h];
  for (int k = 0; k < H_; ++k) accv += x[k] * w[k];
  Y[b * H_ + h] = tanhf(accv);
}

// ---------------------------------------------------------------------------
// Kernel 8: logits = Y @ W2^T + b2 ; logp = log_softmax ; loss = NLL mean
// out[0] = loss ; out[1..32] = logp[16][2]
// ---------------------------------------------------------------------------
__global__ __launch_bounds__(64) void fc2_loss_kernel(
    const float* __restrict__ Y, const float* __restrict__ W2,
    const float* __restrict__ b2, const int* __restrict__ labels,
    float* __restrict__ out)
{
  __shared__ float logp_s[B_][2];
  int t = threadIdx.x;
  if (t < 2 * B_) {
    int b = t >> 1, n = t & 1;
    const float* y = Y + b * H_;
    const float* w = W2 + n * H_;
    float accv = b2[n];
    for (int k = 0; k < H_; ++k) accv += y[k] * w[k];
    logp_s[b][n] = accv;
  }
  __syncthreads();
  if (t < B_) {
    float l0 = logp_s[t][0], l1 = logp_s[t][1];
    float m = fmaxf(l0, l1);
    float lse = m + logf(expf(l0 - m) + expf(l1 - m));
    logp_s[t][0] = l0 - lse;
    logp_s[t][1] = l1 - lse;
  }
  __syncthreads();
  if (t < 2 * B_) out[1 + t] = logp_s[t >> 1][t & 1];
  if (t == 0) {
    float loss = 0.f;
    for (int b = 0; b < B_; ++b) loss -= logp_s[b][labels[b]];
    out[0] = loss / (float)B_;
  }
}

// ---------------------------------------------------------------------------
extern "C" void kernel_launch(void* const* d_in, const int* in_sizes, int n_in,
                              void* d_out, int out_size, void* d_ws, size_t ws_size,
                              hipStream_t stream) {
  const float* q      = (const float*)d_in[0];
  const float* c      = (const float*)d_in[1];
  const int*   mask_q = (const int*)d_in[2];
  const int*   mask_c = (const int*)d_in[3];
  const int*   labels = (const int*)d_in[4];
  const float* W1     = (const float*)d_in[5];
  const float* b1     = (const float*)d_in[6];
  const float* W2     = (const float*)d_in[7];
  const float* b2     = (const float*)d_in[8];
  float* out = (float*)d_out;

  float* ws        = (float*)d_ws;
  float* S         = ws;                          // 16M floats (64 MiB)
  float* rowmax    = ws + (size_t)B_ * SQ_ * SC_; // +16384
  float* rowsum    = rowmax + B_ * SQ_;
  float* colmax    = rowsum + B_ * SQ_;
  float* colsum    = colmax + B_ * SC_;
  float* colsum_p  = colsum + B_ * SC_;
  float* rowsum_pp = colsum_p + B_ * SC_;
  float* X         = rowsum_pp + B_ * SQ_;        // 16*1536
  float* Y         = X + B_ * H_;                 // 16*1536

  dim3 g1(SC_ / 64, SQ_ / 64, B_);
  gemm_mask_kernel<<<g1, 256, 0, stream>>>(q, c, mask_q, mask_c, S);

  row_stats_kernel<<<(B_ * SQ_) / 4, 256, 0, stream>>>(S, rowmax, rowsum);
  col_stats_kernel<<<dim3(SC_ / 256, B_), 256, 0, stream>>>(S, colmax, colsum);
  colsum_p_kernel<<<dim3(SC_ / 256, B_), 256, 0, stream>>>(S, rowmax, rowsum, colsum_p);
  rowsum_pp_kernel<<<(B_ * SQ_) / 4, 256, 0, stream>>>(S, colmax, colsum, rowsum_pp);

  combine_kernel<<<dim3(6, B_), 256, 0, stream>>>(q, c, colsum_p, rowsum_pp, X);
  fc1_kernel<<<(B_ * H_) / 256, 256, 0, stream>>>(X, W1, b1, Y);
  fc2_loss_kernel<<<1, 64, 0, stream>>>(Y, W2, b2, labels, out);
}

// Round 3
// 296.235 us; speedup vs baseline: 3.3531x; 3.3531x over previous
//
#include <hip/hip_runtime.h>
#include <math.h>

#define B_   16
#define SQ_  1024
#define SC_  1024
#define D_   768
#define H_   1536
#define LDK  40   // padded LDS leading dim (bf16 elems) for k-tiles of 32

typedef __attribute__((ext_vector_type(4))) float f32x4;
typedef __attribute__((ext_vector_type(8))) short bf16x8;
typedef __attribute__((ext_vector_type(4))) unsigned short u16x4;

__device__ __forceinline__ unsigned short f2bf(float f) {
  unsigned u = __float_as_uint(f);
  u += 0x7FFFu + ((u >> 16) & 1u);
  return (unsigned short)(u >> 16);
}
__device__ __forceinline__ float bf2f(unsigned short h) {
  return __uint_as_float(((unsigned)h) << 16);
}

// ---------------------------------------------------------------------------
// Kernel 1: S = masked(q . c^T) via split-bf16 MFMA.
// 128x128 tile, 4 waves (each 64x64 = 4x4 frags of 16x16x32), BK=32.
// fp32 -> (hi,lo) bf16 split in registers, staged to padded LDS.
// S ~= Ah*Bh + Ah*Bl + Al*Bh  (lo*lo dropped, ~1e-5 rel err)
// ---------------------------------------------------------------------------
__global__ __launch_bounds__(256) void gemm_mfma_kernel(
    const float* __restrict__ q, const float* __restrict__ c,
    const int* __restrict__ mask_q, const int* __restrict__ mask_c,
    float* __restrict__ S)
{
  __shared__ unsigned short Ah[128][LDK];
  __shared__ unsigned short Al[128][LDK];
  __shared__ unsigned short Bh[128][LDK];
  __shared__ unsigned short Bl[128][LDK];

  const int b  = blockIdx.z;
  const int i0 = blockIdx.y * 128;
  const int j0 = blockIdx.x * 128;
  const int t    = threadIdx.x;
  const int lane = t & 63;
  const int w    = t >> 6;
  const int wr   = w >> 1;   // 0..1
  const int wc   = w & 1;    // 0..1

  const float* qb = q + ((size_t)b * SQ_ + i0) * D_;
  const float* cb = c + ((size_t)b * SC_ + j0) * D_;

  f32x4 acc[4][4] = {};

  const int srow = t >> 3;        // 0..31 (+32 per staging iter)
  const int sc4  = (t & 7) * 4;   // float col offset within k-tile

  const int fr = lane & 15;
  const int kg = (lane >> 4) * 8;

  for (int k0 = 0; k0 < D_; k0 += 32) {
#pragma unroll
    for (int it = 0; it < 4; ++it) {
      int row = srow + it * 32;
      float4 av = *(const float4*)(qb + (size_t)row * D_ + k0 + sc4);
      float4 bv = *(const float4*)(cb + (size_t)row * D_ + k0 + sc4);
      float af[4] = {av.x, av.y, av.z, av.w};
      float bfv[4] = {bv.x, bv.y, bv.z, bv.w};
      u16x4 ah, al, bh, bl;
#pragma unroll
      for (int e = 0; e < 4; ++e) {
        unsigned short h = f2bf(af[e]);  ah[e] = h; al[e] = f2bf(af[e] - bf2f(h));
        unsigned short g = f2bf(bfv[e]); bh[e] = g; bl[e] = f2bf(bfv[e] - bf2f(g));
      }
      *(u16x4*)&Ah[row][sc4] = ah;
      *(u16x4*)&Al[row][sc4] = al;
      *(u16x4*)&Bh[row][sc4] = bh;
      *(u16x4*)&Bl[row][sc4] = bl;
    }
    __syncthreads();

    bf16x8 a_h[4], a_l[4];
#pragma unroll
    for (int m = 0; m < 4; ++m) {
      int r = wr * 64 + m * 16 + fr;
      a_h[m] = *reinterpret_cast<const bf16x8*>(&Ah[r][kg]);
      a_l[m] = *reinterpret_cast<const bf16x8*>(&Al[r][kg]);
    }
#pragma unroll
    for (int n = 0; n < 4; ++n) {
      int r = wc * 64 + n * 16 + fr;
      bf16x8 b_h = *reinterpret_cast<const bf16x8*>(&Bh[r][kg]);
      bf16x8 b_l = *reinterpret_cast<const bf16x8*>(&Bl[r][kg]);
#pragma unroll
      for (int m = 0; m < 4; ++m) {
        acc[m][n] = __builtin_amdgcn_mfma_f32_16x16x32_bf16(a_h[m], b_h, acc[m][n], 0, 0, 0);
        acc[m][n] = __builtin_amdgcn_mfma_f32_16x16x32_bf16(a_h[m], b_l, acc[m][n], 0, 0, 0);
        acc[m][n] = __builtin_amdgcn_mfma_f32_16x16x32_bf16(a_l[m], b_h, acc[m][n], 0, 0, 0);
      }
    }
    __syncthreads();
  }

  // epilogue: mask semantics  s = (mq && mc && s != 0) ? s : -inf
  const int fq = lane >> 4;
#pragma unroll
  for (int m = 0; m < 4; ++m) {
    int rbase = i0 + wr * 64 + m * 16 + fq * 4;
    int mq0 = mask_q[b * SQ_ + rbase + 0];
    int mq1 = mask_q[b * SQ_ + rbase + 1];
    int mq2 = mask_q[b * SQ_ + rbase + 2];
    int mq3 = mask_q[b * SQ_ + rbase + 3];
#pragma unroll
    for (int n = 0; n < 4; ++n) {
      int col = j0 + wc * 64 + n * 16 + fr;
      int mcv = mask_c[b * SC_ + col];
      float* Sp = S + ((size_t)b * SQ_ + rbase) * SC_ + col;
      float v0 = acc[m][n][0], v1 = acc[m][n][1], v2 = acc[m][n][2], v3 = acc[m][n][3];
      Sp[0 * SC_] = (mq0 && mcv && v0 != 0.f) ? v0 : -INFINITY;
      Sp[1 * SC_] = (mq1 && mcv && v1 != 0.f) ? v1 : -INFINITY;
      Sp[2 * SC_] = (mq2 && mcv && v2 != 0.f) ? v2 : -INFINITY;
      Sp[3 * SC_] = (mq3 && mcv && v3 != 0.f) ? v3 : -INFINITY;
    }
  }
}

// ---------------------------------------------------------------------------
// Kernel 2: per-row online (max, sum exp). One wave per row, single pass.
// ---------------------------------------------------------------------------
__global__ __launch_bounds__(256) void row_stats_kernel(
    const float* __restrict__ S, float* __restrict__ rowmax, float* __restrict__ rowsum)
{
  int w    = threadIdx.x >> 6;
  int lane = threadIdx.x & 63;
  int row  = blockIdx.x * 4 + w;   // b*SQ_ + i
  const float4* Sr = (const float4*)(S + (size_t)row * SC_);

  float m = -INFINITY, s = 0.f;
#pragma unroll
  for (int it = 0; it < 4; ++it) {
    float4 v = Sr[it * 64 + lane];
    float vm = fmaxf(fmaxf(v.x, v.y), fmaxf(v.z, v.w));
    if (vm > m) { s *= __expf(m - vm); m = vm; }
    if (m > -INFINITY) {
      s += __expf(v.x - m) + __expf(v.y - m) + __expf(v.z - m) + __expf(v.w - m);
    }
  }
#pragma unroll
  for (int o = 32; o; o >>= 1) {
    float om = __shfl_xor(m, o);
    float os = __shfl_xor(s, o);
    float nm = fmaxf(m, om);
    float e1 = (m == nm) ? 1.f : __expf(m - nm);
    float e2 = (om == nm) ? 1.f : __expf(om - nm);
    s = s * e1 + os * e2;
    m = nm;
  }
  if (lane == 0) { rowmax[row] = m; rowsum[row] = s; }
}

// ---------------------------------------------------------------------------
// Kernel 3 (fused column pass): colmax, colsum AND colsum_p in ONE read of S.
// colsum_p[b,j] = sum_i exp(S - rm'_i) * inv_i  with masked rows encoded as
// (rm' = +inf, inv = 0) so the expression needs no branches.
// Block: (jtile of 64) x (4 i-chunks of 256). Grid (16, B).
// ---------------------------------------------------------------------------
__global__ __launch_bounds__(256) void col_pass_kernel(
    const float* __restrict__ S, const float* __restrict__ rowmax,
    const float* __restrict__ rowsum, float* __restrict__ colmax,
    float* __restrict__ colsum, float* __restrict__ colsum_p)
{
  __shared__ float rmL[SQ_];
  __shared__ float riL[SQ_];
  __shared__ float redm[256], reds[256], redp[256];

  int b  = blockIdx.y;
  int j0 = blockIdx.x * 64;
  int t  = threadIdx.x;

  for (int i = t; i < SQ_; i += 256) {
    float rs = rowsum[b * SQ_ + i];
    bool dead = !(rs > 0.f);
    rmL[i] = dead ? INFINITY : rowmax[b * SQ_ + i];
    riL[i] = dead ? 0.f : 1.f / rs;
  }
  __syncthreads();

  int j   = j0 + (t & 63);
  int ic0 = (t >> 6) * 256;
  const float* Sb = S + ((size_t)b * SQ_ + ic0) * SC_ + j;

  float cm = -INFINITY, cs = 0.f, cp = 0.f;
  for (int ii = 0; ii < 256; ++ii) {
    float v = Sb[(size_t)ii * SC_];
    int i = ic0 + ii;
    cp += __expf(v - rmL[i]) * riL[i];
    if (v > cm) { cs = cs * __expf(cm - v) + 1.0f; cm = v; }
    else if (cm > -INFINITY) cs += __expf(v - cm);
  }

  redm[t] = cm; reds[t] = cs; redp[t] = cp;
  __syncthreads();
  if (t < 64) {
    float m = redm[t], s = reds[t], p = redp[t];
#pragma unroll
    for (int ch = 1; ch < 4; ++ch) {
      float om = redm[ch * 64 + t], os = reds[ch * 64 + t];
      float nm = fmaxf(m, om);
      float e1 = (m == nm) ? 1.f : __expf(m - nm);
      float e2 = (om == nm) ? 1.f : __expf(om - nm);
      s = s * e1 + os * e2; m = nm;
      p += redp[ch * 64 + t];
    }
    colmax[b * SC_ + j0 + t] = m;
    colsum[b * SC_ + j0 + t] = s;
    colsum_p[b * SC_ + j0 + t] = p;
  }
}

// ---------------------------------------------------------------------------
// Kernel 4: rowsum_pp[b,i] = sum_j exp(S - cm'_j) * cinv_j, one wave per row,
// column stats staged in LDS with masked cols as (+inf, 0): branch-free.
// ---------------------------------------------------------------------------
__global__ __launch_bounds__(256) void rowsum_pp_kernel(
    const float* __restrict__ S, const float* __restrict__ colmax,
    const float* __restrict__ colsum, float* __restrict__ rowsum_pp)
{
  __shared__ float cmL[SC_];
  __shared__ float ciL[SC_];

  int t = threadIdx.x;
  int row0 = blockIdx.x * 4;        // 4 rows per block, same b (256 blocks/b)
  int b = row0 >> 10;

  for (int jj = t; jj < SC_; jj += 256) {
    float cs = colsum[b * SC_ + jj];
    bool dead = !(cs > 0.f);
    cmL[jj] = dead ? INFINITY : colmax[b * SC_ + jj];
    ciL[jj] = dead ? 0.f : 1.f / cs;
  }
  __syncthreads();

  int w = t >> 6, lane = t & 63;
  int row = row0 + w;
  const float4* Sr = (const float4*)(S + (size_t)row * SC_);

  float accv = 0.f;
#pragma unroll
  for (int it = 0; it < 4; ++it) {
    float4 v = Sr[it * 64 + lane];
    int j = (it * 64 + lane) * 4;
    accv += __expf(v.x - cmL[j + 0]) * ciL[j + 0];
    accv += __expf(v.y - cmL[j + 1]) * ciL[j + 1];
    accv += __expf(v.z - cmL[j + 2]) * ciL[j + 2];
    accv += __expf(v.w - cmL[j + 3]) * ciL[j + 3];
  }
#pragma unroll
  for (int o = 32; o; o >>= 1) accv += __shfl_xor(accv, o);
  if (lane == 0) rowsum_pp[row] = accv;
}

// ---------------------------------------------------------------------------
// Kernel 5: combine partials. a[b,k] = sum_j cp[j]*c[b,j,k] (op 0),
// bb[b,k] = sum_i rpp[i]*q[b,i,k] (op 1). j split 8-way -> Xp[jc][b][1536].
// Skips j with weight exactly 0 (masked: ~50%), uniform branch.
// ---------------------------------------------------------------------------
__global__ __launch_bounds__(256) void combine_kernel(
    const float* __restrict__ q, const float* __restrict__ c,
    const float* __restrict__ colsum_p, const float* __restrict__ rowsum_pp,
    float* __restrict__ Xp)
{
  int jc = blockIdx.x;   // 0..7
  int op = blockIdx.y;   // 0: c/colsum_p -> X[0:768];  1: q/rowsum_pp -> X[768:]
  int b  = blockIdx.z;
  int t  = threadIdx.x;

  const float* src = op ? (q + (size_t)b * SQ_ * D_) : (c + (size_t)b * SC_ * D_);
  const float* wv  = op ? (rowsum_pp + b * SQ_) : (colsum_p + b * SC_);

  float a0 = 0.f, a1 = 0.f, a2 = 0.f;
  for (int j = jc * 128; j < jc * 128 + 128; ++j) {
    float wj = wv[j];
    if (wj != 0.f) {
      const float* r = src + (size_t)j * D_;
      a0 += wj * r[t];
      a1 += wj * r[t + 256];
      a2 += wj * r[t + 512];
    }
  }
  float* xp = Xp + ((size_t)jc * B_ + b) * H_ + op * D_;
  xp[t] = a0; xp[t + 256] = a1; xp[t + 512] = a2;
}

// ---------------------------------------------------------------------------
// Kernel 6: reduce Xp over 8 chunks -> X[b][1536]
// ---------------------------------------------------------------------------
__global__ __launch_bounds__(256) void reduce_x_kernel(
    const float* __restrict__ Xp, float* __restrict__ X)
{
  int idx = blockIdx.x * 256 + threadIdx.x;   // 0 .. 16*1536-1
  float s = 0.f;
#pragma unroll
  for (int ch = 0; ch < 8; ++ch) s += Xp[(size_t)ch * B_ * H_ + idx];
  X[idx] = s;
}

// ---------------------------------------------------------------------------
// Kernel 7: fc1: Y[b,h] = tanh(X[b,:].W1[h,:] + b1[h]).  One wave per (b,h).
// ---------------------------------------------------------------------------
__global__ __launch_bounds__(256) void fc1_kernel(
    const float* __restrict__ X, const float* __restrict__ W1,
    const float* __restrict__ b1, float* __restrict__ Y)
{
  int w = threadIdx.x >> 6, lane = threadIdx.x & 63;
  int gw = blockIdx.x * 4 + w;          // 0 .. 24575
  int b = gw & 15;
  int h = gw >> 4;
  const float4* x  = (const float4*)(X + (size_t)b * H_);
  const float4* wr = (const float4*)(W1 + (size_t)h * H_);
  float accv = 0.f;
#pragma unroll
  for (int it = 0; it < 6; ++it) {
    int idx = it * 64 + lane;
    float4 xv = x[idx], wv = wr[idx];
    accv += xv.x * wv.x + xv.y * wv.y + xv.z * wv.z + xv.w * wv.w;
  }
#pragma unroll
  for (int o = 32; o; o >>= 1) accv += __shfl_xor(accv, o);
  if (lane == 0) Y[(size_t)b * H_ + h] = tanhf(accv + b1[h]);
}

// ---------------------------------------------------------------------------
// Kernel 8: fc2 + log_softmax + NLL loss.
// ---------------------------------------------------------------------------
__global__ __launch_bounds__(64) void fc2_loss_kernel(
    const float* __restrict__ Y, const float* __restrict__ W2,
    const float* __restrict__ b2, const int* __restrict__ labels,
    float* __restrict__ out)
{
  __shared__ float logp_s[B_][2];
  int t = threadIdx.x;
  if (t < 2 * B_) {
    int b = t >> 1, n = t & 1;
    const float* y = Y + (size_t)b * H_;
    const float* w = W2 + (size_t)n * H_;
    float accv = b2[n];
    for (int k = 0; k < H_; ++k) accv += y[k] * w[k];
    logp_s[b][n] = accv;
  }
  __syncthreads();
  if (t < B_) {
    float l0 = logp_s[t][0], l1 = logp_s[t][1];
    float m = fmaxf(l0, l1);
    float lse = m + logf(expf(l0 - m) + expf(l1 - m));
    logp_s[t][0] = l0 - lse;
    logp_s[t][1] = l1 - lse;
  }
  __syncthreads();
  if (t < 2 * B_) out[1 + t] = logp_s[t >> 1][t & 1];
  if (t == 0) {
    float loss = 0.f;
    for (int b = 0; b < B_; ++b) loss -= logp_s[b][labels[b]];
    out[0] = loss / (float)B_;
  }
}

// ---------------------------------------------------------------------------
extern "C" void kernel_launch(void* const* d_in, const int* in_sizes, int n_in,
                              void* d_out, int out_size, void* d_ws, size_t ws_size,
                              hipStream_t stream) {
  const float* q      = (const float*)d_in[0];
  const float* c      = (const float*)d_in[1];
  const int*   mask_q = (const int*)d_in[2];
  const int*   mask_c = (const int*)d_in[3];
  const int*   labels = (const int*)d_in[4];
  const float* W1     = (const float*)d_in[5];
  const float* b1     = (const float*)d_in[6];
  const float* W2     = (const float*)d_in[7];
  const float* b2     = (const float*)d_in[8];
  float* out = (float*)d_out;

  float* ws        = (float*)d_ws;
  float* S         = ws;                           // 16M floats (64 MiB)
  float* rowmax    = ws + (size_t)B_ * SQ_ * SC_;
  float* rowsum    = rowmax + B_ * SQ_;
  float* colmax    = rowsum + B_ * SQ_;
  float* colsum    = colmax + B_ * SC_;
  float* colsum_p  = colsum + B_ * SC_;
  float* rowsum_pp = colsum_p + B_ * SC_;
  // After rowsum_pp, S is dead: reuse its space for Xp / X / Y.
  float* Xp        = ws;                           // 8*16*1536 floats
  float* X         = ws + 8 * B_ * H_;
  float* Y         = X + B_ * H_;

  dim3 g1(SC_ / 128, SQ_ / 128, B_);
  gemm_mfma_kernel<<<g1, 256, 0, stream>>>(q, c, mask_q, mask_c, S);

  row_stats_kernel<<<(B_ * SQ_) / 4, 256, 0, stream>>>(S, rowmax, rowsum);
  col_pass_kernel<<<dim3(SC_ / 64, B_), 256, 0, stream>>>(S, rowmax, rowsum,
                                                          colmax, colsum, colsum_p);
  rowsum_pp_kernel<<<(B_ * SQ_) / 4, 256, 0, stream>>>(S, colmax, colsum, rowsum_pp);

  combine_kernel<<<dim3(8, 2, B_), 256, 0, stream>>>(q, c, colsum_p, rowsum_pp, Xp);
  reduce_x_kernel<<<(B_ * H_) / 256, 256, 0, stream>>>(Xp, X);
  fc1_kernel<<<(B_ * H_) / 4, 256, 0, stream>>>(X, W1, b1, Y);
  fc2_loss_kernel<<<1, 64, 0, stream>>>(Y, W2, b2, labels, out);
}

// Round 5
// 282.985 us; speedup vs baseline: 3.5101x; 1.0468x over previous
//
#include <hip/hip_runtime.h>
#include <math.h>

#define B_   16
#define SQ_  1024
#define SC_  1024
#define D_   768
#define H_   1536
#define LDK  40   // padded LDS leading dim (bf16 elems) for k-tiles of 32

typedef __attribute__((ext_vector_type(4))) float f32x4;
typedef __attribute__((ext_vector_type(8))) short bf16x8;
typedef __attribute__((ext_vector_type(4))) unsigned short u16x4;

__device__ __forceinline__ unsigned short f2bf(float f) {
  unsigned u = __float_as_uint(f);
  u += 0x7FFFu + ((u >> 16) & 1u);
  return (unsigned short)(u >> 16);
}
__device__ __forceinline__ float bf2f(unsigned short h) {
  return __uint_as_float(((unsigned)h) << 16);
}

// ---------------------------------------------------------------------------
// Kernel 0: per (batch, which) mask compaction. Stable prefix-sum scan.
// ---------------------------------------------------------------------------
__global__ __launch_bounds__(256) void compact_kernel(
    const int* __restrict__ mask_q, const int* __restrict__ mask_c,
    int* __restrict__ idx_q, int* __restrict__ idx_c, int* __restrict__ cnt)
{
  int which = blockIdx.x & 1;   // 0: q, 1: c
  int b     = blockIdx.x >> 1;
  const int* m = (which ? mask_c : mask_q) + b * 1024;
  int* idx     = (which ? idx_c : idx_q) + b * 1024;

  __shared__ int tsum[256];
  int t = threadIdx.x;
  int v[4], s = 0;
#pragma unroll
  for (int e = 0; e < 4; ++e) { v[e] = (m[t * 4 + e] != 0) ? 1 : 0; s += v[e]; }
  tsum[t] = s;
  __syncthreads();
  for (int off = 1; off < 256; off <<= 1) {
    int add = (t >= off) ? tsum[t - off] : 0;
    __syncthreads();
    tsum[t] += add;
    __syncthreads();
  }
  int pos = tsum[t] - s;   // exclusive prefix
#pragma unroll
  for (int e = 0; e < 4; ++e) {
    if (v[e]) idx[pos++] = t * 4 + e;
  }
  if (t == 255) cnt[b * 2 + which] = tsum[255];
}

// ---------------------------------------------------------------------------
// Kernel 1: compact S = masked(q~ . c~^T) via split-bf16 MFMA on VALID rows
// only (gathered through idx). Pads [nq,nq_pad)x[nc,nc_pad) with -inf.
// ---------------------------------------------------------------------------
__global__ __launch_bounds__(256) void gemm_mfma_kernel(
    const float* __restrict__ q, const float* __restrict__ c,
    const int* __restrict__ idx_q, const int* __restrict__ idx_c,
    const int* __restrict__ cnt, float* __restrict__ S)
{
  __shared__ unsigned short Ah[128][LDK];
  __shared__ unsigned short Al[128][LDK];
  __shared__ unsigned short Bh[128][LDK];
  __shared__ unsigned short Bl[128][LDK];

  const int b  = blockIdx.z;
  const int i0 = blockIdx.y * 128;
  const int j0 = blockIdx.x * 128;
  const int nq = cnt[2 * b], nc = cnt[2 * b + 1];
  if (i0 >= nq || j0 >= nc) return;   // block-uniform exit (before barriers)

  const int t    = threadIdx.x;
  const int lane = t & 63;
  const int w    = t >> 6;
  const int wr   = w >> 1;   // 0..1
  const int wc   = w & 1;    // 0..1

  const int srow = t >> 3;        // 0..31 (+32 per staging iter)
  const int sc4  = (t & 7) * 4;   // float col offset within k-tile
  const int fr = lane & 15;
  const int kg = (lane >> 4) * 8;

  // hoist gathered row base pointers (k-independent)
  const float* qrow[4];
  const float* crow[4];
#pragma unroll
  for (int it = 0; it < 4; ++it) {
    int r  = srow + it * 32;
    int rq = idx_q[b * 1024 + min(i0 + r, nq - 1)];
    int rc = idx_c[b * 1024 + min(j0 + r, nc - 1)];
    qrow[it] = q + ((size_t)b * SQ_ + rq) * D_;
    crow[it] = c + ((size_t)b * SC_ + rc) * D_;
  }

  f32x4 acc[4][4] = {};

  for (int k0 = 0; k0 < D_; k0 += 32) {
#pragma unroll
    for (int it = 0; it < 4; ++it) {
      int row = srow + it * 32;
      float4 av = *(const float4*)(qrow[it] + k0 + sc4);
      float4 bv = *(const float4*)(crow[it] + k0 + sc4);
      float af[4]  = {av.x, av.y, av.z, av.w};
      float bfv[4] = {bv.x, bv.y, bv.z, bv.w};
      u16x4 ah, al, bh, bl;
#pragma unroll
      for (int e = 0; e < 4; ++e) {
        unsigned short h = f2bf(af[e]);  ah[e] = h; al[e] = f2bf(af[e] - bf2f(h));
        unsigned short g = f2bf(bfv[e]); bh[e] = g; bl[e] = f2bf(bfv[e] - bf2f(g));
      }
      *(u16x4*)&Ah[row][sc4] = ah;
      *(u16x4*)&Al[row][sc4] = al;
      *(u16x4*)&Bh[row][sc4] = bh;
      *(u16x4*)&Bl[row][sc4] = bl;
    }
    __syncthreads();

    bf16x8 a_h[4], a_l[4];
#pragma unroll
    for (int m = 0; m < 4; ++m) {
      int r = wr * 64 + m * 16 + fr;
      a_h[m] = *reinterpret_cast<const bf16x8*>(&Ah[r][kg]);
      a_l[m] = *reinterpret_cast<const bf16x8*>(&Al[r][kg]);
    }
#pragma unroll
    for (int n = 0; n < 4; ++n) {
      int r = wc * 64 + n * 16 + fr;
      bf16x8 b_h = *reinterpret_cast<const bf16x8*>(&Bh[r][kg]);
      bf16x8 b_l = *reinterpret_cast<const bf16x8*>(&Bl[r][kg]);
#pragma unroll
      for (int m = 0; m < 4; ++m) {
        acc[m][n] = __builtin_amdgcn_mfma_f32_16x16x32_bf16(a_h[m], b_h, acc[m][n], 0, 0, 0);
        acc[m][n] = __builtin_amdgcn_mfma_f32_16x16x32_bf16(a_h[m], b_l, acc[m][n], 0, 0, 0);
        acc[m][n] = __builtin_amdgcn_mfma_f32_16x16x32_bf16(a_l[m], b_h, acc[m][n], 0, 0, 0);
      }
    }
    __syncthreads();
  }

  // epilogue: compact-coords write; -inf outside [0,nq)x[0,nc) and where v==0
  const int fq = lane >> 4;
#pragma unroll
  for (int m = 0; m < 4; ++m) {
    int rbase = i0 + wr * 64 + m * 16 + fq * 4;
#pragma unroll
    for (int n = 0; n < 4; ++n) {
      int col = j0 + wc * 64 + n * 16 + fr;
      bool cok = (col < nc);
      float* Sp = S + ((size_t)b * SQ_ + rbase) * SC_ + col;
#pragma unroll
      for (int rr = 0; rr < 4; ++rr) {
        float v = acc[m][n][rr];
        bool valid = ((rbase + rr) < nq) && cok && (v != 0.f);
        Sp[(size_t)rr * SC_] = valid ? v : -INFINITY;
      }
    }
  }
}

// ---------------------------------------------------------------------------
// Kernel 2: per-row online (max, sum exp) over compact cols. One wave/row.
// Lane-strided loop handles nc_pad being any multiple of 128 (>> not 256).
// ---------------------------------------------------------------------------
__global__ __launch_bounds__(256) void row_stats_kernel(
    const float* __restrict__ S, const int* __restrict__ cnt,
    float* __restrict__ rowmax, float* __restrict__ rowsum)
{
  int w    = threadIdx.x >> 6;
  int lane = threadIdx.x & 63;
  int row  = blockIdx.x * 4 + w;   // b*SQ_ + i
  int b = row >> 10, i = row & 1023;
  int nq_pad = (cnt[2 * b] + 127) & ~127;
  if (i >= nq_pad) return;         // wave-uniform, no barriers in kernel
  int nc_pad = (cnt[2 * b + 1] + 127) & ~127;
  const float4* Sr = (const float4*)(S + (size_t)row * SC_);

  float m = -INFINITY, s = 0.f;
  int n4 = nc_pad >> 2;            // float4 count (multiple of 32)
  for (int j4 = lane; j4 < n4; j4 += 64) {
    float4 v = Sr[j4];
    float vm = fmaxf(fmaxf(v.x, v.y), fmaxf(v.z, v.w));
    if (vm > m) { s *= __expf(m - vm); m = vm; }
    if (m > -INFINITY) {
      s += __expf(v.x - m) + __expf(v.y - m) + __expf(v.z - m) + __expf(v.w - m);
    }
  }
#pragma unroll
  for (int o = 32; o; o >>= 1) {
    float om = __shfl_xor(m, o);
    float os = __shfl_xor(s, o);
    float nm = fmaxf(m, om);
    float e1 = (m == nm) ? 1.f : __expf(m - nm);
    float e2 = (om == nm) ? 1.f : __expf(om - nm);
    s = s * e1 + os * e2;
    m = nm;
  }
  if (lane == 0) { rowmax[row] = m; rowsum[row] = s; }
}

// ---------------------------------------------------------------------------
// Kernel 3: fused column pass -> colmax, colsum, colsum_p in one read of S.
// Masked/dead rows encoded (rm=+inf, inv=0): (-inf)-(+inf) = -inf, exp->0.
// ---------------------------------------------------------------------------
__global__ __launch_bounds__(256) void col_pass_kernel(
    const float* __restrict__ S, const int* __restrict__ cnt,
    const float* __restrict__ rowmax, const float* __restrict__ rowsum,
    float* __restrict__ colmax, float* __restrict__ colsum,
    float* __restrict__ colsum_p)
{
  __shared__ float rmL[SQ_];
  __shared__ float riL[SQ_];
  __shared__ float redm[256], reds[256], redp[256];

  int b  = blockIdx.y;
  int j0 = blockIdx.x * 64;
  int nq_pad = (cnt[2 * b] + 127) & ~127;
  int nc_pad = (cnt[2 * b + 1] + 127) & ~127;
  if (j0 >= nc_pad) return;        // block-uniform exit before barriers
  int t  = threadIdx.x;

  for (int i = t; i < nq_pad; i += 256) {
    float rs = rowsum[b * SQ_ + i];
    bool dead = !(rs > 0.f);
    rmL[i] = dead ? INFINITY : rowmax[b * SQ_ + i];
    riL[i] = dead ? 0.f : 1.f / rs;
  }
  __syncthreads();

  int j   = j0 + (t & 63);
  int ic0 = (t >> 6) * 256;                      // wave-uniform chunk base
  int cnt_i = min(256, max(0, nq_pad - ic0));    // wave-uniform trip count
  const float* Sb = S + ((size_t)b * SQ_ + ic0) * SC_ + j;

  float cm = -INFINITY, cs = 0.f, cp = 0.f;
  for (int ii = 0; ii < cnt_i; ++ii) {
    float v = Sb[(size_t)ii * SC_];
    int i = ic0 + ii;
    cp += __expf(v - rmL[i]) * riL[i];
    if (v > cm) { cs = cs * __expf(cm - v) + 1.0f; cm = v; }
    else if (cm > -INFINITY) cs += __expf(v - cm);
  }

  redm[t] = cm; reds[t] = cs; redp[t] = cp;
  __syncthreads();
  if (t < 64) {
    float m = redm[t], s = reds[t], p = redp[t];
#pragma unroll
    for (int ch = 1; ch < 4; ++ch) {
      float om = redm[ch * 64 + t], os = reds[ch * 64 + t];
      float nm = fmaxf(m, om);
      float e1 = (m == nm) ? 1.f : __expf(m - nm);
      float e2 = (om == nm) ? 1.f : __expf(om - nm);
      s = s * e1 + os * e2; m = nm;
      p += redp[ch * 64 + t];
    }
    colmax[b * SC_ + j0 + t] = m;
    colsum[b * SC_ + j0 + t] = s;
    colsum_p[b * SC_ + j0 + t] = p;
  }
}

// ---------------------------------------------------------------------------
// Kernel 4: rowsum_pp[b,i] = sum_j exp(S - cm'_j) * cinv_j over compact cols.
// Lane-strided loop (same 128-granularity fix as kernel 2).
// ---------------------------------------------------------------------------
__global__ __launch_bounds__(256) void rowsum_pp_kernel(
    const float* __restrict__ S, const int* __restrict__ cnt,
    const float* __restrict__ colmax, const float* __restrict__ colsum,
    float* __restrict__ rowsum_pp)
{
  __shared__ float cmL[SC_];
  __shared__ float ciL[SC_];

  int t = threadIdx.x;
  int row0 = blockIdx.x * 4;        // 4 rows per block, same b
  int b = row0 >> 10;
  int nq = cnt[2 * b];
  if ((row0 & 1023) >= nq) return;  // block-uniform exit before barriers
  int nc_pad = (cnt[2 * b + 1] + 127) & ~127;

  for (int jj = t; jj < nc_pad; jj += 256) {
    float cs = colsum[b * SC_ + jj];
    bool dead = !(cs > 0.f);
    cmL[jj] = dead ? INFINITY : colmax[b * SC_ + jj];
    ciL[jj] = dead ? 0.f : 1.f / cs;
  }
  __syncthreads();

  int w = t >> 6, lane = t & 63;
  int row = row0 + w;
  const float4* Sr = (const float4*)(S + (size_t)row * SC_);

  float accv = 0.f;
  int n4 = nc_pad >> 2;             // float4 count (multiple of 32)
  for (int j4 = lane; j4 < n4; j4 += 64) {
    float4 v = Sr[j4];
    int j = j4 * 4;
    accv += __expf(v.x - cmL[j + 0]) * ciL[j + 0];
    accv += __expf(v.y - cmL[j + 1]) * ciL[j + 1];
    accv += __expf(v.z - cmL[j + 2]) * ciL[j + 2];
    accv += __expf(v.w - cmL[j + 3]) * ciL[j + 3];
  }
#pragma unroll
  for (int o = 32; o; o >>= 1) accv += __shfl_xor(accv, o);
  if (lane == 0) rowsum_pp[row] = accv;
}

// ---------------------------------------------------------------------------
// Kernel 5: combine partials over VALID rows via idx gather.
// ---------------------------------------------------------------------------
__global__ __launch_bounds__(256) void combine_kernel(
    const float* __restrict__ q, const float* __restrict__ c,
    const int* __restrict__ idx_q, const int* __restrict__ idx_c,
    const int* __restrict__ cnt,
    const float* __restrict__ colsum_p, const float* __restrict__ rowsum_pp,
    float* __restrict__ Xp)
{
  int jc = blockIdx.x;   // 0..7
  int op = blockIdx.y;   // 0: c/colsum_p ; 1: q/rowsum_pp
  int b  = blockIdx.z;
  int t  = threadIdx.x;

  int n = op ? cnt[2 * b] : cnt[2 * b + 1];
  const float* src = op ? (q + (size_t)b * SQ_ * D_) : (c + (size_t)b * SC_ * D_);
  const float* wv  = op ? (rowsum_pp + b * SQ_) : (colsum_p + b * SC_);
  const int*   idx = (op ? idx_q : idx_c) + b * 1024;

  float a0 = 0.f, a1 = 0.f, a2 = 0.f;
  int je = min(jc * 128 + 128, n);
  for (int j = jc * 128; j < je; ++j) {
    float wj = wv[j];
    const float* r = src + (size_t)idx[j] * D_;
    a0 += wj * r[t];
    a1 += wj * r[t + 256];
    a2 += wj * r[t + 512];
  }
  float* xp = Xp + ((size_t)jc * B_ + b) * H_ + op * D_;
  xp[t] = a0; xp[t + 256] = a1; xp[t + 512] = a2;
}

// ---------------------------------------------------------------------------
// Kernel 6: reduce Xp over 8 chunks -> X[b][1536]
// ---------------------------------------------------------------------------
__global__ __launch_bounds__(256) void reduce_x_kernel(
    const float* __restrict__ Xp, float* __restrict__ X)
{
  int idx = blockIdx.x * 256 + threadIdx.x;
  float s = 0.f;
#pragma unroll
  for (int ch = 0; ch < 8; ++ch) s += Xp[(size_t)ch * B_ * H_ + idx];
  X[idx] = s;
}

// ---------------------------------------------------------------------------
// Kernel 7: fc1: Y[b,h] = tanh(X[b,:].W1[h,:] + b1[h]). One wave per (b,h).
// ---------------------------------------------------------------------------
__global__ __launch_bounds__(256) void fc1_kernel(
    const float* __restrict__ X, const float* __restrict__ W1,
    const float* __restrict__ b1, float* __restrict__ Y)
{
  int w = threadIdx.x >> 6, lane = threadIdx.x & 63;
  int gw = blockIdx.x * 4 + w;
  int b = gw & 15;
  int h = gw >> 4;
  const float4* x  = (const float4*)(X + (size_t)b * H_);
  const float4* wr = (const float4*)(W1 + (size_t)h * H_);
  float accv = 0.f;
#pragma unroll
  for (int it = 0; it < 6; ++it) {
    int idx = it * 64 + lane;
    float4 xv = x[idx], wv = wr[idx];
    accv += xv.x * wv.x + xv.y * wv.y + xv.z * wv.z + xv.w * wv.w;
  }
#pragma unroll
  for (int o = 32; o; o >>= 1) accv += __shfl_xor(accv, o);
  if (lane == 0) Y[(size_t)b * H_ + h] = tanhf(accv + b1[h]);
}

// ---------------------------------------------------------------------------
// Kernel 8: fc2 + log_softmax + NLL loss.
// ---------------------------------------------------------------------------
__global__ __launch_bounds__(64) void fc2_loss_kernel(
    const float* __restrict__ Y, const float* __restrict__ W2,
    const float* __restrict__ b2, const int* __restrict__ labels,
    float* __restrict__ out)
{
  __shared__ float logp_s[B_][2];
  int t = threadIdx.x;
  if (t < 2 * B_) {
    int b = t >> 1, n = t & 1;
    const float* y = Y + (size_t)b * H_;
    const float* w = W2 + (size_t)n * H_;
    float accv = b2[n];
    for (int k = 0; k < H_; ++k) accv += y[k] * w[k];
    logp_s[b][n] = accv;
  }
  __syncthreads();
  if (t < B_) {
    float l0 = logp_s[t][0], l1 = logp_s[t][1];
    float m = fmaxf(l0, l1);
    float lse = m + logf(expf(l0 - m) + expf(l1 - m));
    logp_s[t][0] = l0 - lse;
    logp_s[t][1] = l1 - lse;
  }
  __syncthreads();
  if (t < 2 * B_) out[1 + t] = logp_s[t >> 1][t & 1];
  if (t == 0) {
    float loss = 0.f;
    for (int b = 0; b < B_; ++b) loss -= logp_s[b][labels[b]];
    out[0] = loss / (float)B_;
  }
}

// ---------------------------------------------------------------------------
extern "C" void kernel_launch(void* const* d_in, const int* in_sizes, int n_in,
                              void* d_out, int out_size, void* d_ws, size_t ws_size,
                              hipStream_t stream) {
  const float* q      = (const float*)d_in[0];
  const float* c      = (const float*)d_in[1];
  const int*   mask_q = (const int*)d_in[2];
  const int*   mask_c = (const int*)d_in[3];
  const int*   labels = (const int*)d_in[4];
  const float* W1     = (const float*)d_in[5];
  const float* b1     = (const float*)d_in[6];
  const float* W2     = (const float*)d_in[7];
  const float* b2     = (const float*)d_in[8];
  float* out = (float*)d_out;

  float* ws        = (float*)d_ws;
  float* S         = ws;                           // 16M floats (64 MiB)
  float* rowmax    = ws + (size_t)B_ * SQ_ * SC_;
  float* rowsum    = rowmax + B_ * SQ_;
  float* colmax    = rowsum + B_ * SQ_;
  float* colsum    = colmax + B_ * SC_;
  float* colsum_p  = colsum + B_ * SC_;
  float* rowsum_pp = colsum_p + B_ * SC_;
  int*   cnt       = (int*)(rowsum_pp + B_ * SQ_);
  int*   idx_q     = cnt + 2 * B_;
  int*   idx_c     = idx_q + B_ * SQ_;
  // After rowsum_pp, S is dead: reuse its space for Xp / X / Y.
  float* Xp        = ws;                           // 8*16*1536 floats
  float* X         = ws + 8 * B_ * H_;
  float* Y         = X + B_ * H_;

  compact_kernel<<<2 * B_, 256, 0, stream>>>(mask_q, mask_c, idx_q, idx_c, cnt);

  dim3 g1(SC_ / 128, SQ_ / 128, B_);
  gemm_mfma_kernel<<<g1, 256, 0, stream>>>(q, c, idx_q, idx_c, cnt, S);

  row_stats_kernel<<<(B_ * SQ_) / 4, 256, 0, stream>>>(S, cnt, rowmax, rowsum);
  col_pass_kernel<<<dim3(SC_ / 64, B_), 256, 0, stream>>>(S, cnt, rowmax, rowsum,
                                                          colmax, colsum, colsum_p);
  rowsum_pp_kernel<<<(B_ * SQ_) / 4, 256, 0, stream>>>(S, cnt, colmax, colsum, rowsum_pp);

  combine_kernel<<<dim3(8, 2, B_), 256, 0, stream>>>(q, c, idx_q, idx_c, cnt,
                                                     colsum_p, rowsum_pp, Xp);
  reduce_x_kernel<<<(B_ * H_) / 256, 256, 0, stream>>>(Xp, X);
  fc1_kernel<<<(B_ * H_) / 4, 256, 0, stream>>>(X, W1, b1, Y);
  fc2_loss_kernel<<<1, 64, 0, stream>>>(Y, W2, b2, labels, out);
}

// Round 6
// 260.144 us; speedup vs baseline: 3.8183x; 1.0878x over previous
//
#include <hip/hip_runtime.h>
#include <math.h>

#define B_   16
#define SQ_  1024
#define SC_  1024
#define D_   768
#define H_   1536
#define LDK  40   // padded LDS leading dim (bf16 elems) for k-tiles of 32

typedef __attribute__((ext_vector_type(4))) float f32x4;
typedef __attribute__((ext_vector_type(8))) short bf16x8;
typedef __attribute__((ext_vector_type(4))) unsigned short u16x4;

__device__ __forceinline__ unsigned short f2bf(float f) {
  unsigned u = __float_as_uint(f);
  u += 0x7FFFu + ((u >> 16) & 1u);
  return (unsigned short)(u >> 16);
}
__device__ __forceinline__ float bf2f(unsigned short h) {
  return __uint_as_float(((unsigned)h) << 16);
}

// ---------------------------------------------------------------------------
// Kernel 0: per (batch, which) mask compaction. Stable prefix-sum scan.
// ---------------------------------------------------------------------------
__global__ __launch_bounds__(256) void compact_kernel(
    const int* __restrict__ mask_q, const int* __restrict__ mask_c,
    int* __restrict__ idx_q, int* __restrict__ idx_c, int* __restrict__ cnt)
{
  int which = blockIdx.x & 1;   // 0: q, 1: c
  int b     = blockIdx.x >> 1;
  const int* m = (which ? mask_c : mask_q) + b * 1024;
  int* idx     = (which ? idx_c : idx_q) + b * 1024;

  __shared__ int tsum[256];
  int t = threadIdx.x;
  int v[4], s = 0;
#pragma unroll
  for (int e = 0; e < 4; ++e) { v[e] = (m[t * 4 + e] != 0) ? 1 : 0; s += v[e]; }
  tsum[t] = s;
  __syncthreads();
  for (int off = 1; off < 256; off <<= 1) {
    int add = (t >= off) ? tsum[t - off] : 0;
    __syncthreads();
    tsum[t] += add;
    __syncthreads();
  }
  int pos = tsum[t] - s;   // exclusive prefix
#pragma unroll
  for (int e = 0; e < 4; ++e) {
    if (v[e]) idx[pos++] = t * 4 + e;
  }
  if (t == 255) cnt[b * 2 + which] = tsum[255];
}

// ---------------------------------------------------------------------------
// Kernel 1: compact S = masked(q~ . c~^T), split-bf16 MFMA, 64x64 tiles.
// 4 waves; wave w computes 64 rows x 16 cols (4 m-frags, n-frag = w).
// ~1024 active blocks (4/CU) for latency hiding. Pads to 64 with -inf.
// ---------------------------------------------------------------------------
__global__ __launch_bounds__(256) void gemm_mfma_kernel(
    const float* __restrict__ q, const float* __restrict__ c,
    const int* __restrict__ idx_q, const int* __restrict__ idx_c,
    const int* __restrict__ cnt, float* __restrict__ S)
{
  __shared__ unsigned short Ah[64][LDK];
  __shared__ unsigned short Al[64][LDK];
  __shared__ unsigned short Bh[64][LDK];
  __shared__ unsigned short Bl[64][LDK];

  const int b  = blockIdx.z;
  const int i0 = blockIdx.y * 64;
  const int j0 = blockIdx.x * 64;
  const int nq = cnt[2 * b], nc = cnt[2 * b + 1];
  if (i0 >= nq || j0 >= nc) return;   // block-uniform exit (before barriers)

  const int t    = threadIdx.x;
  const int lane = t & 63;
  const int w    = t >> 6;            // 0..3 = n-frag

  const int srow = t >> 2;            // 0..63 staging row
  const int kc   = (t & 3) * 4;       // k sub-offset (float4); also +16
  const int fr   = lane & 15;
  const int fq   = lane >> 4;
  const int kg   = fq * 8;

  const int rq = idx_q[b * 1024 + min(i0 + srow, nq - 1)];
  const int rc = idx_c[b * 1024 + min(j0 + srow, nc - 1)];
  const float* qrowP = q + ((size_t)b * SQ_ + rq) * D_;
  const float* crowP = c + ((size_t)b * SC_ + rc) * D_;

  f32x4 acc[4] = {};

  for (int k0 = 0; k0 < D_; k0 += 32) {
    float4 a0v = *(const float4*)(qrowP + k0 + kc);
    float4 a1v = *(const float4*)(qrowP + k0 + kc + 16);
    float4 b0v = *(const float4*)(crowP + k0 + kc);
    float4 b1v = *(const float4*)(crowP + k0 + kc + 16);
    float a0f[4] = {a0v.x, a0v.y, a0v.z, a0v.w};
    float a1f[4] = {a1v.x, a1v.y, a1v.z, a1v.w};
    float b0f[4] = {b0v.x, b0v.y, b0v.z, b0v.w};
    float b1f[4] = {b1v.x, b1v.y, b1v.z, b1v.w};
    u16x4 ah0, al0, ah1, al1, bh0, bl0, bh1, bl1;
#pragma unroll
    for (int e = 0; e < 4; ++e) {
      unsigned short h;
      h = f2bf(a0f[e]); ah0[e] = h; al0[e] = f2bf(a0f[e] - bf2f(h));
      h = f2bf(a1f[e]); ah1[e] = h; al1[e] = f2bf(a1f[e] - bf2f(h));
      h = f2bf(b0f[e]); bh0[e] = h; bl0[e] = f2bf(b0f[e] - bf2f(h));
      h = f2bf(b1f[e]); bh1[e] = h; bl1[e] = f2bf(b1f[e] - bf2f(h));
    }
    __syncthreads();   // protect LDS from previous iteration's readers
    *(u16x4*)&Ah[srow][kc]      = ah0;
    *(u16x4*)&Ah[srow][kc + 16] = ah1;
    *(u16x4*)&Al[srow][kc]      = al0;
    *(u16x4*)&Al[srow][kc + 16] = al1;
    *(u16x4*)&Bh[srow][kc]      = bh0;
    *(u16x4*)&Bh[srow][kc + 16] = bh1;
    *(u16x4*)&Bl[srow][kc]      = bl0;
    *(u16x4*)&Bl[srow][kc + 16] = bl1;
    __syncthreads();

    bf16x8 b_h = *reinterpret_cast<const bf16x8*>(&Bh[w * 16 + fr][kg]);
    bf16x8 b_l = *reinterpret_cast<const bf16x8*>(&Bl[w * 16 + fr][kg]);
#pragma unroll
    for (int m = 0; m < 4; ++m) {
      bf16x8 a_h = *reinterpret_cast<const bf16x8*>(&Ah[m * 16 + fr][kg]);
      bf16x8 a_l = *reinterpret_cast<const bf16x8*>(&Al[m * 16 + fr][kg]);
      acc[m] = __builtin_amdgcn_mfma_f32_16x16x32_bf16(a_h, b_h, acc[m], 0, 0, 0);
      acc[m] = __builtin_amdgcn_mfma_f32_16x16x32_bf16(a_h, b_l, acc[m], 0, 0, 0);
      acc[m] = __builtin_amdgcn_mfma_f32_16x16x32_bf16(a_l, b_h, acc[m], 0, 0, 0);
    }
  }

  // epilogue: C/D layout col=lane&15, row=(lane>>4)*4+reg (+16 per m-frag)
  const int col = j0 + w * 16 + fr;
  const bool cok = (col < nc);
#pragma unroll
  for (int m = 0; m < 4; ++m) {
    int rbase = i0 + m * 16 + fq * 4;
    float* Sp = S + ((size_t)b * SQ_ + rbase) * SC_ + col;
#pragma unroll
    for (int rr = 0; rr < 4; ++rr) {
      float v = acc[m][rr];
      bool valid = ((rbase + rr) < nq) && cok && (v != 0.f);
      Sp[(size_t)rr * SC_] = valid ? v : -INFINITY;
    }
  }
}

// ---------------------------------------------------------------------------
// Kernel 2: per-row online (max, sum exp); writes ENCODED stats:
// rmE = +inf (dead) else rowmax ; riE = 0 (dead) else 1/rowsum.
// ---------------------------------------------------------------------------
__global__ __launch_bounds__(256) void row_stats_kernel(
    const float* __restrict__ S, const int* __restrict__ cnt,
    float* __restrict__ rmE, float* __restrict__ riE)
{
  int w    = threadIdx.x >> 6;
  int lane = threadIdx.x & 63;
  int row  = blockIdx.x * 4 + w;   // b*SQ_ + i
  int b = row >> 10, i = row & 1023;
  int nq_pad = (cnt[2 * b] + 63) & ~63;
  if (i >= nq_pad) return;         // wave-uniform, no barriers in kernel
  int nc_pad = (cnt[2 * b + 1] + 63) & ~63;
  const float4* Sr = (const float4*)(S + (size_t)row * SC_);

  float m = -INFINITY, s = 0.f;
  int n4 = nc_pad >> 2;            // float4 count (multiple of 16)
  for (int j4 = lane; j4 < n4; j4 += 64) {
    float4 v = Sr[j4];
    float vm = fmaxf(fmaxf(v.x, v.y), fmaxf(v.z, v.w));
    if (vm > m) { s *= __expf(m - vm); m = vm; }
    if (m > -INFINITY) {
      s += __expf(v.x - m) + __expf(v.y - m) + __expf(v.z - m) + __expf(v.w - m);
    }
  }
#pragma unroll
  for (int o = 32; o; o >>= 1) {
    float om = __shfl_xor(m, o);
    float os = __shfl_xor(s, o);
    float nm = fmaxf(m, om);
    float e1 = (m == nm) ? 1.f : __expf(m - nm);
    float e2 = (om == nm) ? 1.f : __expf(om - nm);
    s = s * e1 + os * e2;
    m = nm;
  }
  if (lane == 0) {
    bool dead = !(s > 0.f);
    rmE[row] = dead ? INFINITY : m;
    riE[row] = dead ? 0.f : 1.0f / s;
  }
}

// ---------------------------------------------------------------------------
// Kernel 3: fused column pass -> encoded cmE/ciE AND colsum_p, one S read.
// Row encodings read straight from global (wave-uniform index, cached).
// ---------------------------------------------------------------------------
__global__ __launch_bounds__(256) void col_pass_kernel(
    const float* __restrict__ S, const int* __restrict__ cnt,
    const float* __restrict__ rmE, const float* __restrict__ riE,
    float* __restrict__ cmE, float* __restrict__ ciE,
    float* __restrict__ colsum_p)
{
  __shared__ float redm[256], reds[256], redp[256];

  int b  = blockIdx.y;
  int j0 = blockIdx.x * 64;
  int nq_pad = (cnt[2 * b] + 63) & ~63;
  int nc_pad = (cnt[2 * b + 1] + 63) & ~63;
  if (j0 >= nc_pad) return;        // block-uniform exit before barriers
  int t  = threadIdx.x;

  int j   = j0 + (t & 63);
  int ic0 = (t >> 6) * 256;                      // wave-uniform chunk base
  int cnt_i = min(256, max(0, nq_pad - ic0));    // wave-uniform trip count
  const float* Sb = S + ((size_t)b * SQ_ + ic0) * SC_ + j;
  const float* rmb = rmE + b * SQ_ + ic0;
  const float* rib = riE + b * SQ_ + ic0;

  float cm = -INFINITY, cs = 0.f, cp = 0.f;
  for (int ii = 0; ii < cnt_i; ++ii) {
    float v = Sb[(size_t)ii * SC_];
    cp += __expf(v - rmb[ii]) * rib[ii];
    if (v > cm) { cs = cs * __expf(cm - v) + 1.0f; cm = v; }
    else if (cm > -INFINITY) cs += __expf(v - cm);
  }

  redm[t] = cm; reds[t] = cs; redp[t] = cp;
  __syncthreads();
  if (t < 64) {
    float m = redm[t], s = reds[t], p = redp[t];
#pragma unroll
    for (int ch = 1; ch < 4; ++ch) {
      float om = redm[ch * 64 + t], os = reds[ch * 64 + t];
      float nm = fmaxf(m, om);
      float e1 = (m == nm) ? 1.f : __expf(m - nm);
      float e2 = (om == nm) ? 1.f : __expf(om - nm);
      s = s * e1 + os * e2; m = nm;
      p += redp[ch * 64 + t];
    }
    bool dead = !(s > 0.f);
    cmE[b * SC_ + j0 + t] = dead ? INFINITY : m;
    ciE[b * SC_ + j0 + t] = dead ? 0.f : 1.0f / s;
    colsum_p[b * SC_ + j0 + t] = p;
  }
}

// ---------------------------------------------------------------------------
// Kernel 4: rowsum_pp[b,i] = sum_j exp(S - cmE_j) * ciE_j. Pure streaming,
// col encodings via float4 global loads (L1-resident), no LDS/barriers.
// ---------------------------------------------------------------------------
__global__ __launch_bounds__(256) void rowsum_pp_kernel(
    const float* __restrict__ S, const int* __restrict__ cnt,
    const float* __restrict__ cmE, const float* __restrict__ ciE,
    float* __restrict__ rowsum_pp)
{
  int t = threadIdx.x;
  int row0 = blockIdx.x * 4;        // 4 rows per block, same b
  int b = row0 >> 10;
  int nq = cnt[2 * b];
  if ((row0 & 1023) >= nq) return;
  int nc_pad = (cnt[2 * b + 1] + 63) & ~63;

  int w = t >> 6, lane = t & 63;
  int row = row0 + w;
  const float4* Sr  = (const float4*)(S + (size_t)row * SC_);
  const float4* cm4 = (const float4*)(cmE + b * SC_);
  const float4* ci4 = (const float4*)(ciE + b * SC_);

  float accv = 0.f;
  int n4 = nc_pad >> 2;             // float4 count (multiple of 16)
  for (int j4 = lane; j4 < n4; j4 += 64) {
    float4 v = Sr[j4];
    float4 cm = cm4[j4];
    float4 ci = ci4[j4];
    accv += __expf(v.x - cm.x) * ci.x;
    accv += __expf(v.y - cm.y) * ci.y;
    accv += __expf(v.z - cm.z) * ci.z;
    accv += __expf(v.w - cm.w) * ci.w;
  }
#pragma unroll
  for (int o = 32; o; o >>= 1) accv += __shfl_xor(accv, o);
  if (lane == 0) rowsum_pp[row] = accv;
}

// ---------------------------------------------------------------------------
// Kernel 5: combine partials over VALID rows via idx gather.
// ---------------------------------------------------------------------------
__global__ __launch_bounds__(256) void combine_kernel(
    const float* __restrict__ q, const float* __restrict__ c,
    const int* __restrict__ idx_q, const int* __restrict__ idx_c,
    const int* __restrict__ cnt,
    const float* __restrict__ colsum_p, const float* __restrict__ rowsum_pp,
    float* __restrict__ Xp)
{
  int jc = blockIdx.x;   // 0..7
  int op = blockIdx.y;   // 0: c/colsum_p ; 1: q/rowsum_pp
  int b  = blockIdx.z;
  int t  = threadIdx.x;

  int n = op ? cnt[2 * b] : cnt[2 * b + 1];
  const float* src = op ? (q + (size_t)b * SQ_ * D_) : (c + (size_t)b * SC_ * D_);
  const float* wv  = op ? (rowsum_pp + b * SQ_) : (colsum_p + b * SC_);
  const int*   idx = (op ? idx_q : idx_c) + b * 1024;

  float a0 = 0.f, a1 = 0.f, a2 = 0.f;
  int je = min(jc * 128 + 128, n);
  for (int j = jc * 128; j < je; ++j) {
    float wj = wv[j];
    const float* r = src + (size_t)idx[j] * D_;
    a0 += wj * r[t];
    a1 += wj * r[t + 256];
    a2 += wj * r[t + 512];
  }
  float* xp = Xp + ((size_t)jc * B_ + b) * H_ + op * D_;
  xp[t] = a0; xp[t + 256] = a1; xp[t + 512] = a2;
}

// ---------------------------------------------------------------------------
// Kernel 6: reduce Xp over 8 chunks -> X[b][1536]
// ---------------------------------------------------------------------------
__global__ __launch_bounds__(256) void reduce_x_kernel(
    const float* __restrict__ Xp, float* __restrict__ X)
{
  int idx = blockIdx.x * 256 + threadIdx.x;
  float s = 0.f;
#pragma unroll
  for (int ch = 0; ch < 8; ++ch) s += Xp[(size_t)ch * B_ * H_ + idx];
  X[idx] = s;
}

// ---------------------------------------------------------------------------
// Kernel 7: fc1: Y[b,h] = tanh(X[b,:].W1[h,:] + b1[h]). One wave per (b,h).
// ---------------------------------------------------------------------------
__global__ __launch_bounds__(256) void fc1_kernel(
    const float* __restrict__ X, const float* __restrict__ W1,
    const float* __restrict__ b1, float* __restrict__ Y)
{
  int w = threadIdx.x >> 6, lane = threadIdx.x & 63;
  int gw = blockIdx.x * 4 + w;
  int b = gw & 15;
  int h = gw >> 4;
  const float4* x  = (const float4*)(X + (size_t)b * H_);
  const float4* wr = (const float4*)(W1 + (size_t)h * H_);
  float accv = 0.f;
#pragma unroll
  for (int it = 0; it < 6; ++it) {
    int idx = it * 64 + lane;
    float4 xv = x[idx], wv = wr[idx];
    accv += xv.x * wv.x + xv.y * wv.y + xv.z * wv.z + xv.w * wv.w;
  }
#pragma unroll
  for (int o = 32; o; o >>= 1) accv += __shfl_xor(accv, o);
  if (lane == 0) Y[(size_t)b * H_ + h] = tanhf(accv + b1[h]);
}

// ---------------------------------------------------------------------------
// Kernel 8: fc2 + log_softmax + NLL loss.
// ---------------------------------------------------------------------------
__global__ __launch_bounds__(64) void fc2_loss_kernel(
    const float* __restrict__ Y, const float* __restrict__ W2,
    const float* __restrict__ b2, const int* __restrict__ labels,
    float* __restrict__ out)
{
  __shared__ float logp_s[B_][2];
  int t = threadIdx.x;
  if (t < 2 * B_) {
    int b = t >> 1, n = t & 1;
    const float* y = Y + (size_t)b * H_;
    const float* w = W2 + (size_t)n * H_;
    float accv = b2[n];
    for (int k = 0; k < H_; ++k) accv += y[k] * w[k];
    logp_s[b][n] = accv;
  }
  __syncthreads();
  if (t < B_) {
    float l0 = logp_s[t][0], l1 = logp_s[t][1];
    float m = fmaxf(l0, l1);
    float lse = m + logf(expf(l0 - m) + expf(l1 - m));
    logp_s[t][0] = l0 - lse;
    logp_s[t][1] = l1 - lse;
  }
  __syncthreads();
  if (t < 2 * B_) out[1 + t] = logp_s[t >> 1][t & 1];
  if (t == 0) {
    float loss = 0.f;
    for (int b = 0; b < B_; ++b) loss -= logp_s[b][labels[b]];
    out[0] = loss / (float)B_;
  }
}

// ---------------------------------------------------------------------------
extern "C" void kernel_launch(void* const* d_in, const int* in_sizes, int n_in,
                              void* d_out, int out_size, void* d_ws, size_t ws_size,
                              hipStream_t stream) {
  const float* q      = (const float*)d_in[0];
  const float* c      = (const float*)d_in[1];
  const int*   mask_q = (const int*)d_in[2];
  const int*   mask_c = (const int*)d_in[3];
  const int*   labels = (const int*)d_in[4];
  const float* W1     = (const float*)d_in[5];
  const float* b1     = (const float*)d_in[6];
  const float* W2     = (const float*)d_in[7];
  const float* b2     = (const float*)d_in[8];
  float* out = (float*)d_out;

  float* ws        = (float*)d_ws;
  float* S         = ws;                           // 16M floats (64 MiB)
  float* rmE       = ws + (size_t)B_ * SQ_ * SC_;
  float* riE       = rmE + B_ * SQ_;
  float* cmE       = riE + B_ * SQ_;
  float* ciE       = cmE + B_ * SC_;
  float* colsum_p  = ciE + B_ * SC_;
  float* rowsum_pp = colsum_p + B_ * SC_;
  int*   cnt       = (int*)(rowsum_pp + B_ * SQ_);
  int*   idx_q     = cnt + 2 * B_;
  int*   idx_c     = idx_q + B_ * SQ_;
  // After rowsum_pp, S is dead: reuse its space for Xp / X / Y.
  float* Xp        = ws;                           // 8*16*1536 floats
  float* X         = ws + 8 * B_ * H_;
  float* Y         = X + B_ * H_;

  compact_kernel<<<2 * B_, 256, 0, stream>>>(mask_q, mask_c, idx_q, idx_c, cnt);

  dim3 g1(SC_ / 64, SQ_ / 64, B_);
  gemm_mfma_kernel<<<g1, 256, 0, stream>>>(q, c, idx_q, idx_c, cnt, S);

  row_stats_kernel<<<(B_ * SQ_) / 4, 256, 0, stream>>>(S, cnt, rmE, riE);
  col_pass_kernel<<<dim3(SC_ / 64, B_), 256, 0, stream>>>(S, cnt, rmE, riE,
                                                          cmE, ciE, colsum_p);
  rowsum_pp_kernel<<<(B_ * SQ_) / 4, 256, 0, stream>>>(S, cnt, cmE, ciE, rowsum_pp);

  combine_kernel<<<dim3(8, 2, B_), 256, 0, stream>>>(q, c, idx_q, idx_c, cnt,
                                                     colsum_p, rowsum_pp, Xp);
  reduce_x_kernel<<<(B_ * H_) / 256, 256, 0, stream>>>(Xp, X);
  fc1_kernel<<<(B_ * H_) / 4, 256, 0, stream>>>(X, W1, b1, Y);
  fc2_loss_kernel<<<1, 64, 0, stream>>>(Y, W2, b2, labels, out);
}

// Round 7
// 180.886 us; speedup vs baseline: 5.4913x; 1.4382x over previous
//
#include <hip/hip_runtime.h>
#include <math.h>

#define B_   16
#define SQ_  1024
#define SC_  1024
#define D_   768
#define H_   1536
#define BK   64   // k-tile
#define LDK  72   // padded LDS leading dim (bf16 elems) for k-tiles of 64

typedef __attribute__((ext_vector_type(4))) float f32x4;
typedef __attribute__((ext_vector_type(8))) short bf16x8;

// packed f32x2 -> bf16x2 (RNE), low16 = bf16(x), high16 = bf16(y)
__device__ __forceinline__ unsigned cvtpk(float x, float y) {
  unsigned r;
  asm("v_cvt_pk_bf16_f32 %0, %1, %2" : "=v"(r) : "v"(x), "v"(y));
  return r;
}

// ---------------------------------------------------------------------------
// Kernel 0: per (batch, which) mask compaction. Stable prefix-sum scan.
// ---------------------------------------------------------------------------
__global__ __launch_bounds__(256) void compact_kernel(
    const int* __restrict__ mask_q, const int* __restrict__ mask_c,
    int* __restrict__ idx_q, int* __restrict__ idx_c, int* __restrict__ cnt)
{
  int which = blockIdx.x & 1;   // 0: q, 1: c
  int b     = blockIdx.x >> 1;
  const int* m = (which ? mask_c : mask_q) + b * 1024;
  int* idx     = (which ? idx_c : idx_q) + b * 1024;

  __shared__ int tsum[256];
  int t = threadIdx.x;
  int v[4], s = 0;
#pragma unroll
  for (int e = 0; e < 4; ++e) { v[e] = (m[t * 4 + e] != 0) ? 1 : 0; s += v[e]; }
  tsum[t] = s;
  __syncthreads();
  for (int off = 1; off < 256; off <<= 1) {
    int add = (t >= off) ? tsum[t - off] : 0;
    __syncthreads();
    tsum[t] += add;
    __syncthreads();
  }
  int pos = tsum[t] - s;   // exclusive prefix
#pragma unroll
  for (int e = 0; e < 4; ++e) {
    if (v[e]) idx[pos++] = t * 4 + e;
  }
  if (t == 255) cnt[b * 2 + which] = tsum[255];
}

// ---------------------------------------------------------------------------
// Kernel 1: compact S = masked(q~ . c~^T), split-bf16 MFMA, 64x64 tiles,
// BK=64, cvt_pk-based hi/lo conversion (3 VALU/elem).
// ---------------------------------------------------------------------------
__global__ __launch_bounds__(256) void gemm_mfma_kernel(
    const float* __restrict__ q, const float* __restrict__ c,
    const int* __restrict__ idx_q, const int* __restrict__ idx_c,
    const int* __restrict__ cnt, float* __restrict__ S)
{
  __shared__ unsigned short Ah[64][LDK];
  __shared__ unsigned short Al[64][LDK];
  __shared__ unsigned short Bh[64][LDK];
  __shared__ unsigned short Bl[64][LDK];

  const int b  = blockIdx.z;
  const int i0 = blockIdx.y * 64;
  const int j0 = blockIdx.x * 64;
  const int nq = cnt[2 * b], nc = cnt[2 * b + 1];
  if (i0 >= nq || j0 >= nc) return;   // block-uniform exit (before barriers)

  const int t    = threadIdx.x;
  const int lane = t & 63;
  const int w    = t >> 6;            // 0..3 = n-frag

  const int srow = t >> 2;            // 0..63 staging row
  const int kq4  = (t & 3) * 4;       // k sub-offset within 16
  const int fr   = lane & 15;
  const int fq   = lane >> 4;
  const int kg   = fq * 8;

  const int rq = idx_q[b * 1024 + min(i0 + srow, nq - 1)];
  const int rc = idx_c[b * 1024 + min(j0 + srow, nc - 1)];
  const float* qrowP = q + ((size_t)b * SQ_ + rq) * D_;
  const float* crowP = c + ((size_t)b * SC_ + rc) * D_;

  f32x4 acc[4] = {};

  for (int k0 = 0; k0 < D_; k0 += BK) {
    uint2 aH[4], aL[4], bH[4], bL[4];
#pragma unroll
    for (int ch = 0; ch < 4; ++ch) {
      int koff = k0 + kq4 + ch * 16;
      float4 av = *(const float4*)(qrowP + koff);
      float4 bv = *(const float4*)(crowP + koff);
      // hi via packed cvt, lo = x - hi (exact), then packed cvt of lo
      unsigned h01 = cvtpk(av.x, av.y);
      unsigned h23 = cvtpk(av.z, av.w);
      float h0 = __uint_as_float(h01 << 16);
      float h1 = __uint_as_float(h01 & 0xFFFF0000u);
      float h2 = __uint_as_float(h23 << 16);
      float h3 = __uint_as_float(h23 & 0xFFFF0000u);
      aH[ch] = make_uint2(h01, h23);
      aL[ch] = make_uint2(cvtpk(av.x - h0, av.y - h1), cvtpk(av.z - h2, av.w - h3));
      unsigned g01 = cvtpk(bv.x, bv.y);
      unsigned g23 = cvtpk(bv.z, bv.w);
      float g0 = __uint_as_float(g01 << 16);
      float g1 = __uint_as_float(g01 & 0xFFFF0000u);
      float g2 = __uint_as_float(g23 << 16);
      float g3 = __uint_as_float(g23 & 0xFFFF0000u);
      bH[ch] = make_uint2(g01, g23);
      bL[ch] = make_uint2(cvtpk(bv.x - g0, bv.y - g1), cvtpk(bv.z - g2, bv.w - g3));
    }
    __syncthreads();   // protect LDS from previous iteration's readers
#pragma unroll
    for (int ch = 0; ch < 4; ++ch) {
      int koff = kq4 + ch * 16;
      *(uint2*)&Ah[srow][koff] = aH[ch];
      *(uint2*)&Al[srow][koff] = aL[ch];
      *(uint2*)&Bh[srow][koff] = bH[ch];
      *(uint2*)&Bl[srow][koff] = bL[ch];
    }
    __syncthreads();

#pragma unroll
    for (int ksub = 0; ksub < 2; ++ksub) {
      const int kg2 = kg + ksub * 32;
      bf16x8 b_h = *reinterpret_cast<const bf16x8*>(&Bh[w * 16 + fr][kg2]);
      bf16x8 b_l = *reinterpret_cast<const bf16x8*>(&Bl[w * 16 + fr][kg2]);
#pragma unroll
      for (int m = 0; m < 4; ++m) {
        bf16x8 a_h = *reinterpret_cast<const bf16x8*>(&Ah[m * 16 + fr][kg2]);
        bf16x8 a_l = *reinterpret_cast<const bf16x8*>(&Al[m * 16 + fr][kg2]);
        acc[m] = __builtin_amdgcn_mfma_f32_16x16x32_bf16(a_h, b_h, acc[m], 0, 0, 0);
        acc[m] = __builtin_amdgcn_mfma_f32_16x16x32_bf16(a_h, b_l, acc[m], 0, 0, 0);
        acc[m] = __builtin_amdgcn_mfma_f32_16x16x32_bf16(a_l, b_h, acc[m], 0, 0, 0);
      }
    }
  }

  // epilogue: C/D layout col=lane&15, row=(lane>>4)*4+reg (+16 per m-frag)
  const int col = j0 + w * 16 + fr;
  const bool cok = (col < nc);
#pragma unroll
  for (int m = 0; m < 4; ++m) {
    int rbase = i0 + m * 16 + fq * 4;
    float* Sp = S + ((size_t)b * SQ_ + rbase) * SC_ + col;
#pragma unroll
    for (int rr = 0; rr < 4; ++rr) {
      float v = acc[m][rr];
      bool valid = ((rbase + rr) < nq) && cok && (v != 0.f);
      Sp[(size_t)rr * SC_] = valid ? v : -INFINITY;
    }
  }
}

// ---------------------------------------------------------------------------
// Kernel 2: per-row online (max, sum exp); writes ENCODED stats:
// rmE = +inf (dead) else rowmax ; riE = 0 (dead) else 1/rowsum.
// ---------------------------------------------------------------------------
__global__ __launch_bounds__(256) void row_stats_kernel(
    const float* __restrict__ S, const int* __restrict__ cnt,
    float* __restrict__ rmE, float* __restrict__ riE)
{
  int w    = threadIdx.x >> 6;
  int lane = threadIdx.x & 63;
  int row  = blockIdx.x * 4 + w;   // b*SQ_ + i
  int b = row >> 10, i = row & 1023;
  int nq_pad = (cnt[2 * b] + 63) & ~63;
  if (i >= nq_pad) return;         // wave-uniform, no barriers in kernel
  int nc_pad = (cnt[2 * b + 1] + 63) & ~63;
  const float4* Sr = (const float4*)(S + (size_t)row * SC_);

  float m = -INFINITY, s = 0.f;
  int n4 = nc_pad >> 2;            // float4 count (multiple of 16)
  for (int j4 = lane; j4 < n4; j4 += 64) {
    float4 v = Sr[j4];
    float vm = fmaxf(fmaxf(v.x, v.y), fmaxf(v.z, v.w));
    if (vm > m) { s *= __expf(m - vm); m = vm; }
    if (m > -INFINITY) {
      s += __expf(v.x - m) + __expf(v.y - m) + __expf(v.z - m) + __expf(v.w - m);
    }
  }
#pragma unroll
  for (int o = 32; o; o >>= 1) {
    float om = __shfl_xor(m, o);
    float os = __shfl_xor(s, o);
    float nm = fmaxf(m, om);
    float e1 = (m == nm) ? 1.f : __expf(m - nm);
    float e2 = (om == nm) ? 1.f : __expf(om - nm);
    s = s * e1 + os * e2;
    m = nm;
  }
  if (lane == 0) {
    bool dead = !(s > 0.f);
    rmE[row] = dead ? INFINITY : m;
    riE[row] = dead ? 0.f : 1.0f / s;
  }
}

// ---------------------------------------------------------------------------
// Kernel 3: fused column pass -> encoded cmE/ciE AND colsum_p, one S read.
// 1024 threads: 16 waves each own nq_pad/16 rows; LDS merge. Grid (16, B).
// ---------------------------------------------------------------------------
__global__ __launch_bounds__(1024) void col_pass_kernel(
    const float* __restrict__ S, const int* __restrict__ cnt,
    const float* __restrict__ rmE, const float* __restrict__ riE,
    float* __restrict__ cmE, float* __restrict__ ciE,
    float* __restrict__ colsum_p)
{
  __shared__ float redm[1024], reds[1024], redp[1024];

  int b  = blockIdx.y;
  int j0 = blockIdx.x * 64;
  int nq_pad = (cnt[2 * b] + 63) & ~63;
  int nc_pad = (cnt[2 * b + 1] + 63) & ~63;
  if (j0 >= nc_pad) return;        // block-uniform exit before barriers
  int t  = threadIdx.x;

  int j     = j0 + (t & 63);
  int wv    = t >> 6;                        // 0..15
  int chunk = nq_pad >> 4;                   // rows per wave (mult of 4)
  int i0    = wv * chunk;
  const float* Sb  = S + ((size_t)b * SQ_ + i0) * SC_ + j;
  const float* rmb = rmE + b * SQ_ + i0;
  const float* rib = riE + b * SQ_ + i0;

  float cm = -INFINITY, cs = 0.f, cp = 0.f;
  for (int ii = 0; ii < chunk; ++ii) {
    float v = Sb[(size_t)ii * SC_];
    cp += __expf(v - rmb[ii]) * rib[ii];
    if (v > cm) { cs = cs * __expf(cm - v) + 1.0f; cm = v; }
    else if (cm > -INFINITY) cs += __expf(v - cm);
  }

  redm[t] = cm; reds[t] = cs; redp[t] = cp;
  __syncthreads();
  if (t < 64) {
    float m = redm[t], s = reds[t], p = redp[t];
#pragma unroll
    for (int wv2 = 1; wv2 < 16; ++wv2) {
      float om = redm[wv2 * 64 + t], os = reds[wv2 * 64 + t];
      float nm = fmaxf(m, om);
      float e1 = (m == nm) ? 1.f : __expf(m - nm);
      float e2 = (om == nm) ? 1.f : __expf(om - nm);
      s = s * e1 + os * e2; m = nm;
      p += redp[wv2 * 64 + t];
    }
    bool dead = !(s > 0.f);
    cmE[b * SC_ + j0 + t] = dead ? INFINITY : m;
    ciE[b * SC_ + j0 + t] = dead ? 0.f : 1.0f / s;
    colsum_p[b * SC_ + j0 + t] = p;
  }
}

// ---------------------------------------------------------------------------
// Kernel 4: rowsum_pp[b,i] = sum_j exp(S - cmE_j) * ciE_j. Pure streaming.
// ---------------------------------------------------------------------------
__global__ __launch_bounds__(256) void rowsum_pp_kernel(
    const float* __restrict__ S, const int* __restrict__ cnt,
    const float* __restrict__ cmE, const float* __restrict__ ciE,
    float* __restrict__ rowsum_pp)
{
  int t = threadIdx.x;
  int row0 = blockIdx.x * 4;        // 4 rows per block, same b
  int b = row0 >> 10;
  int nq = cnt[2 * b];
  if ((row0 & 1023) >= nq) return;
  int nc_pad = (cnt[2 * b + 1] + 63) & ~63;

  int w = t >> 6, lane = t & 63;
  int row = row0 + w;
  const float4* Sr  = (const float4*)(S + (size_t)row * SC_);
  const float4* cm4 = (const float4*)(cmE + b * SC_);
  const float4* ci4 = (const float4*)(ciE + b * SC_);

  float accv = 0.f;
  int n4 = nc_pad >> 2;             // float4 count (multiple of 16)
  for (int j4 = lane; j4 < n4; j4 += 64) {
    float4 v = Sr[j4];
    float4 cm = cm4[j4];
    float4 ci = ci4[j4];
    accv += __expf(v.x - cm.x) * ci.x;
    accv += __expf(v.y - cm.y) * ci.y;
    accv += __expf(v.z - cm.z) * ci.z;
    accv += __expf(v.w - cm.w) * ci.w;
  }
#pragma unroll
  for (int o = 32; o; o >>= 1) accv += __shfl_xor(accv, o);
  if (lane == 0) rowsum_pp[row] = accv;
}

// ---------------------------------------------------------------------------
// Kernel 5: combine partials over VALID rows via idx gather. 32 j-chunks.
// ---------------------------------------------------------------------------
__global__ __launch_bounds__(256) void combine_kernel(
    const float* __restrict__ q, const float* __restrict__ c,
    const int* __restrict__ idx_q, const int* __restrict__ idx_c,
    const int* __restrict__ cnt,
    const float* __restrict__ colsum_p, const float* __restrict__ rowsum_pp,
    float* __restrict__ Xp)
{
  int jc = blockIdx.x;   // 0..31
  int op = blockIdx.y;   // 0: c/colsum_p ; 1: q/rowsum_pp
  int b  = blockIdx.z;
  int t  = threadIdx.x;

  int n = op ? cnt[2 * b] : cnt[2 * b + 1];
  const float* src = op ? (q + (size_t)b * SQ_ * D_) : (c + (size_t)b * SC_ * D_);
  const float* wv  = op ? (rowsum_pp + b * SQ_) : (colsum_p + b * SC_);
  const int*   idx = (op ? idx_q : idx_c) + b * 1024;

  float a0 = 0.f, a1 = 0.f, a2 = 0.f;
  int je = min(jc * 32 + 32, n);
  for (int j = jc * 32; j < je; ++j) {
    float wj = wv[j];
    const float* r = src + (size_t)idx[j] * D_;
    a0 += wj * r[t];
    a1 += wj * r[t + 256];
    a2 += wj * r[t + 512];
  }
  float* xp = Xp + ((size_t)jc * B_ + b) * H_ + op * D_;
  xp[t] = a0; xp[t + 256] = a1; xp[t + 512] = a2;
}

// ---------------------------------------------------------------------------
// Kernel 6: reduce Xp over 32 chunks -> X[b][1536]
// ---------------------------------------------------------------------------
__global__ __launch_bounds__(256) void reduce_x_kernel(
    const float* __restrict__ Xp, float* __restrict__ X)
{
  int idx = blockIdx.x * 256 + threadIdx.x;
  float s = 0.f;
#pragma unroll
  for (int ch = 0; ch < 32; ++ch) s += Xp[(size_t)ch * B_ * H_ + idx];
  X[idx] = s;
}

// ---------------------------------------------------------------------------
// Kernel 7: fc1: Y[b,h] = tanh(X[b,:].W1[h,:] + b1[h]). One wave per (b,h).
// ---------------------------------------------------------------------------
__global__ __launch_bounds__(256) void fc1_kernel(
    const float* __restrict__ X, const float* __restrict__ W1,
    const float* __restrict__ b1, float* __restrict__ Y)
{
  int w = threadIdx.x >> 6, lane = threadIdx.x & 63;
  int gw = blockIdx.x * 4 + w;
  int b = gw & 15;
  int h = gw >> 4;
  const float4* x  = (const float4*)(X + (size_t)b * H_);
  const float4* wr = (const float4*)(W1 + (size_t)h * H_);
  float accv = 0.f;
#pragma unroll
  for (int it = 0; it < 6; ++it) {
    int idx = it * 64 + lane;
    float4 xv = x[idx], wv = wr[idx];
    accv += xv.x * wv.x + xv.y * wv.y + xv.z * wv.z + xv.w * wv.w;
  }
#pragma unroll
  for (int o = 32; o; o >>= 1) accv += __shfl_xor(accv, o);
  if (lane == 0) Y[(size_t)b * H_ + h] = tanhf(accv + b1[h]);
}

// ---------------------------------------------------------------------------
// Kernel 8: fc2 + log_softmax + NLL loss.
// ---------------------------------------------------------------------------
__global__ __launch_bounds__(64) void fc2_loss_kernel(
    const float* __restrict__ Y, const float* __restrict__ W2,
    const float* __restrict__ b2, const int* __restrict__ labels,
    float* __restrict__ out)
{
  __shared__ float logp_s[B_][2];
  int t = threadIdx.x;
  if (t < 2 * B_) {
    int b = t >> 1, n = t & 1;
    const float* y = Y + (size_t)b * H_;
    const float* w = W2 + (size_t)n * H_;
    float accv = b2[n];
    for (int k = 0; k < H_; ++k) accv += y[k] * w[k];
    logp_s[b][n] = accv;
  }
  __syncthreads();
  if (t < B_) {
    float l0 = logp_s[t][0], l1 = logp_s[t][1];
    float m = fmaxf(l0, l1);
    float lse = m + logf(expf(l0 - m) + expf(l1 - m));
    logp_s[t][0] = l0 - lse;
    logp_s[t][1] = l1 - lse;
  }
  __syncthreads();
  if (t < 2 * B_) out[1 + t] = logp_s[t >> 1][t & 1];
  if (t == 0) {
    float loss = 0.f;
    for (int b = 0; b < B_; ++b) loss -= logp_s[b][labels[b]];
    out[0] = loss / (float)B_;
  }
}

// ---------------------------------------------------------------------------
extern "C" void kernel_launch(void* const* d_in, const int* in_sizes, int n_in,
                              void* d_out, int out_size, void* d_ws, size_t ws_size,
                              hipStream_t stream) {
  const float* q      = (const float*)d_in[0];
  const float* c      = (const float*)d_in[1];
  const int*   mask_q = (const int*)d_in[2];
  const int*   mask_c = (const int*)d_in[3];
  const int*   labels = (const int*)d_in[4];
  const float* W1     = (const float*)d_in[5];
  const float* b1     = (const float*)d_in[6];
  const float* W2     = (const float*)d_in[7];
  const float* b2     = (const float*)d_in[8];
  float* out = (float*)d_out;

  float* ws        = (float*)d_ws;
  float* S         = ws;                           // 16M floats (64 MiB)
  float* rmE       = ws + (size_t)B_ * SQ_ * SC_;
  float* riE       = rmE + B_ * SQ_;
  float* cmE       = riE + B_ * SQ_;
  float* ciE       = cmE + B_ * SC_;
  float* colsum_p  = ciE + B_ * SC_;
  float* rowsum_pp = colsum_p + B_ * SC_;
  int*   cnt       = (int*)(rowsum_pp + B_ * SQ_);
  int*   idx_q     = cnt + 2 * B_;
  int*   idx_c     = idx_q + B_ * SQ_;
  // After rowsum_pp, S is dead: reuse its space for Xp / X / Y.
  float* Xp        = ws;                           // 32*16*1536 floats (3 MiB)
  float* X         = ws + 32 * B_ * H_;
  float* Y         = X + B_ * H_;

  compact_kernel<<<2 * B_, 256, 0, stream>>>(mask_q, mask_c, idx_q, idx_c, cnt);

  dim3 g1(SC_ / 64, SQ_ / 64, B_);
  gemm_mfma_kernel<<<g1, 256, 0, stream>>>(q, c, idx_q, idx_c, cnt, S);

  row_stats_kernel<<<(B_ * SQ_) / 4, 256, 0, stream>>>(S, cnt, rmE, riE);
  col_pass_kernel<<<dim3(SC_ / 64, B_), 1024, 0, stream>>>(S, cnt, rmE, riE,
                                                           cmE, ciE, colsum_p);
  rowsum_pp_kernel<<<(B_ * SQ_) / 4, 256, 0, stream>>>(S, cnt, cmE, ciE, rowsum_pp);

  combine_kernel<<<dim3(32, 2, B_), 256, 0, stream>>>(q, c, idx_q, idx_c, cnt,
                                                      colsum_p, rowsum_pp, Xp);
  reduce_x_kernel<<<(B_ * H_) / 256, 256, 0, stream>>>(Xp, X);
  fc1_kernel<<<(B_ * H_) / 4, 256, 0, stream>>>(X, W1, b1, Y);
  fc2_loss_kernel<<<1, 64, 0, stream>>>(Y, W2, b2, labels, out);
}

// Round 8
// 158.411 us; speedup vs baseline: 6.2704x; 1.1419x over previous
//
#include <hip/hip_runtime.h>
#include <math.h>

#define B_   16
#define SQ_  1024
#define SC_  1024
#define D_   768
#define H_   1536
#define BK   32   // k-tile
#define LDK  40   // padded LDS leading dim (bf16 elems) for k-tiles of 32

typedef __attribute__((ext_vector_type(4))) float f32x4;
typedef __attribute__((ext_vector_type(8))) short bf16x8;

// packed f32x2 -> bf16x2 (RNE), low16 = bf16(x), high16 = bf16(y)
__device__ __forceinline__ unsigned cvtpk(float x, float y) {
  unsigned r;
  asm("v_cvt_pk_bf16_f32 %0, %1, %2" : "=v"(r) : "v"(x), "v"(y));
  return r;
}

// split float4 -> (hi bf16x4, lo bf16x4); lo = x - hi exactly representable
__device__ __forceinline__ void split4(float4 v, uint2& hi, uint2& lo) {
  unsigned h01 = cvtpk(v.x, v.y);
  unsigned h23 = cvtpk(v.z, v.w);
  float h0 = __uint_as_float(h01 << 16);
  float h1 = __uint_as_float(h01 & 0xFFFF0000u);
  float h2 = __uint_as_float(h23 << 16);
  float h3 = __uint_as_float(h23 & 0xFFFF0000u);
  hi = make_uint2(h01, h23);
  lo = make_uint2(cvtpk(v.x - h0, v.y - h1), cvtpk(v.z - h2, v.w - h3));
}

// ---------------------------------------------------------------------------
// Kernel 0: per (batch, which) mask compaction. Stable prefix-sum scan.
// ---------------------------------------------------------------------------
__global__ __launch_bounds__(256) void compact_kernel(
    const int* __restrict__ mask_q, const int* __restrict__ mask_c,
    int* __restrict__ idx_q, int* __restrict__ idx_c, int* __restrict__ cnt)
{
  int which = blockIdx.x & 1;   // 0: q, 1: c
  int b     = blockIdx.x >> 1;
  const int* m = (which ? mask_c : mask_q) + b * 1024;
  int* idx     = (which ? idx_c : idx_q) + b * 1024;

  __shared__ int tsum[256];
  int t = threadIdx.x;
  int v[4], s = 0;
#pragma unroll
  for (int e = 0; e < 4; ++e) { v[e] = (m[t * 4 + e] != 0) ? 1 : 0; s += v[e]; }
  tsum[t] = s;
  __syncthreads();
  for (int off = 1; off < 256; off <<= 1) {
    int add = (t >= off) ? tsum[t - off] : 0;
    __syncthreads();
    tsum[t] += add;
    __syncthreads();
  }
  int pos = tsum[t] - s;   // exclusive prefix
#pragma unroll
  for (int e = 0; e < 4; ++e) {
    if (v[e]) idx[pos++] = t * 4 + e;
  }
  if (t == 255) cnt[b * 2 + which] = tsum[255];
}

// ---------------------------------------------------------------------------
// Kernel 1: compact S = masked(q~ . c~^T), split-bf16 MFMA, 64x64 tiles,
// BK=32, DOUBLE-BUFFERED LDS + register prefetch: one barrier per k-iter,
// global loads for tile k+1 issued before MFMA of tile k.
// ---------------------------------------------------------------------------
__global__ __launch_bounds__(256) void gemm_mfma_kernel(
    const float* __restrict__ q, const float* __restrict__ c,
    const int* __restrict__ idx_q, const int* __restrict__ idx_c,
    const int* __restrict__ cnt, float* __restrict__ S)
{
  __shared__ unsigned short Ah[2][64][LDK];
  __shared__ unsigned short Al[2][64][LDK];
  __shared__ unsigned short Bh[2][64][LDK];
  __shared__ unsigned short Bl[2][64][LDK];   // 2*4*64*40*2 = 40960 B

  const int b  = blockIdx.z;
  const int i0 = blockIdx.y * 64;
  const int j0 = blockIdx.x * 64;
  const int nq = cnt[2 * b], nc = cnt[2 * b + 1];
  if (i0 >= nq || j0 >= nc) return;   // block-uniform exit (before barriers)

  const int t    = threadIdx.x;
  const int lane = t & 63;
  const int w    = t >> 6;            // 0..3 = n-frag

  const int srow = t >> 2;            // 0..63 staging row
  const int kc   = (t & 3) * 4;       // k sub-offset; this thread covers kc and kc+16
  const int fr   = lane & 15;
  const int fq   = lane >> 4;
  const int kg   = fq * 8;

  const int rq = idx_q[b * 1024 + min(i0 + srow, nq - 1)];
  const int rc = idx_c[b * 1024 + min(j0 + srow, nc - 1)];
  const float* qrowP = q + ((size_t)b * SQ_ + rq) * D_;
  const float* crowP = c + ((size_t)b * SC_ + rc) * D_;

  f32x4 acc[4] = {};

  // ---- prologue: load+convert+store k-tile 0 into buf 0
  float4 av0 = *(const float4*)(qrowP + kc);
  float4 av1 = *(const float4*)(qrowP + kc + 16);
  float4 bv0 = *(const float4*)(crowP + kc);
  float4 bv1 = *(const float4*)(crowP + kc + 16);
  {
    uint2 hi, lo;
    split4(av0, hi, lo); *(uint2*)&Ah[0][srow][kc]      = hi; *(uint2*)&Al[0][srow][kc]      = lo;
    split4(av1, hi, lo); *(uint2*)&Ah[0][srow][kc + 16] = hi; *(uint2*)&Al[0][srow][kc + 16] = lo;
    split4(bv0, hi, lo); *(uint2*)&Bh[0][srow][kc]      = hi; *(uint2*)&Bl[0][srow][kc]      = lo;
    split4(bv1, hi, lo); *(uint2*)&Bh[0][srow][kc + 16] = hi; *(uint2*)&Bl[0][srow][kc + 16] = lo;
  }
  __syncthreads();

  int cur = 0;
  for (int k0 = 0; k0 < D_; k0 += BK) {
    const int next = k0 + BK;
    const bool has_next = (next < D_);
    if (has_next) {   // issue next tile's loads early (latency hides under MFMA)
      av0 = *(const float4*)(qrowP + next + kc);
      av1 = *(const float4*)(qrowP + next + kc + 16);
      bv0 = *(const float4*)(crowP + next + kc);
      bv1 = *(const float4*)(crowP + next + kc + 16);
    }

    bf16x8 b_h = *reinterpret_cast<const bf16x8*>(&Bh[cur][w * 16 + fr][kg]);
    bf16x8 b_l = *reinterpret_cast<const bf16x8*>(&Bl[cur][w * 16 + fr][kg]);
#pragma unroll
    for (int m = 0; m < 4; ++m) {
      bf16x8 a_h = *reinterpret_cast<const bf16x8*>(&Ah[cur][m * 16 + fr][kg]);
      bf16x8 a_l = *reinterpret_cast<const bf16x8*>(&Al[cur][m * 16 + fr][kg]);
      acc[m] = __builtin_amdgcn_mfma_f32_16x16x32_bf16(a_h, b_h, acc[m], 0, 0, 0);
      acc[m] = __builtin_amdgcn_mfma_f32_16x16x32_bf16(a_h, b_l, acc[m], 0, 0, 0);
      acc[m] = __builtin_amdgcn_mfma_f32_16x16x32_bf16(a_l, b_h, acc[m], 0, 0, 0);
    }

    if (has_next) {   // convert + store into the OTHER buffer (no conflict)
      int nxt = cur ^ 1;
      uint2 hi, lo;
      split4(av0, hi, lo); *(uint2*)&Ah[nxt][srow][kc]      = hi; *(uint2*)&Al[nxt][srow][kc]      = lo;
      split4(av1, hi, lo); *(uint2*)&Ah[nxt][srow][kc + 16] = hi; *(uint2*)&Al[nxt][srow][kc + 16] = lo;
      split4(bv0, hi, lo); *(uint2*)&Bh[nxt][srow][kc]      = hi; *(uint2*)&Bl[nxt][srow][kc]      = lo;
      split4(bv1, hi, lo); *(uint2*)&Bh[nxt][srow][kc + 16] = hi; *(uint2*)&Bl[nxt][srow][kc + 16] = lo;
    }
    __syncthreads();   // single barrier per iteration
    cur ^= 1;
  }

  // epilogue: C/D layout col=lane&15, row=(lane>>4)*4+reg (+16 per m-frag)
  const int col = j0 + w * 16 + fr;
  const bool cok = (col < nc);
#pragma unroll
  for (int m = 0; m < 4; ++m) {
    int rbase = i0 + m * 16 + fq * 4;
    float* Sp = S + ((size_t)b * SQ_ + rbase) * SC_ + col;
#pragma unroll
    for (int rr = 0; rr < 4; ++rr) {
      float v = acc[m][rr];
      bool valid = ((rbase + rr) < nq) && cok && (v != 0.f);
      Sp[(size_t)rr * SC_] = valid ? v : -INFINITY;
    }
  }
}

// ---------------------------------------------------------------------------
// Kernel 2: per-row online (max, sum exp); writes ENCODED stats:
// rmE = +inf (dead) else rowmax ; riE = 0 (dead) else 1/rowsum.
// ---------------------------------------------------------------------------
__global__ __launch_bounds__(256) void row_stats_kernel(
    const float* __restrict__ S, const int* __restrict__ cnt,
    float* __restrict__ rmE, float* __restrict__ riE)
{
  int w    = threadIdx.x >> 6;
  int lane = threadIdx.x & 63;
  int row  = blockIdx.x * 4 + w;   // b*SQ_ + i
  int b = row >> 10, i = row & 1023;
  int nq_pad = (cnt[2 * b] + 63) & ~63;
  if (i >= nq_pad) return;         // wave-uniform, no barriers in kernel
  int nc_pad = (cnt[2 * b + 1] + 63) & ~63;
  const float4* Sr = (const float4*)(S + (size_t)row * SC_);

  float m = -INFINITY, s = 0.f;
  int n4 = nc_pad >> 2;            // float4 count (multiple of 16)
  for (int j4 = lane; j4 < n4; j4 += 64) {
    float4 v = Sr[j4];
    float vm = fmaxf(fmaxf(v.x, v.y), fmaxf(v.z, v.w));
    if (vm > m) { s *= __expf(m - vm); m = vm; }
    if (m > -INFINITY) {
      s += __expf(v.x - m) + __expf(v.y - m) + __expf(v.z - m) + __expf(v.w - m);
    }
  }
#pragma unroll
  for (int o = 32; o; o >>= 1) {
    float om = __shfl_xor(m, o);
    float os = __shfl_xor(s, o);
    float nm = fmaxf(m, om);
    float e1 = (m == nm) ? 1.f : __expf(m - nm);
    float e2 = (om == nm) ? 1.f : __expf(om - nm);
    s = s * e1 + os * e2;
    m = nm;
  }
  if (lane == 0) {
    bool dead = !(s > 0.f);
    rmE[row] = dead ? INFINITY : m;
    riE[row] = dead ? 0.f : 1.0f / s;
  }
}

// ---------------------------------------------------------------------------
// Kernel 3: fused column pass -> encoded cmE/ciE AND colsum_p, one S read.
// 1024 threads: 16 waves each own nq_pad/16 rows; LDS merge. Grid (16, B).
// ---------------------------------------------------------------------------
__global__ __launch_bounds__(1024) void col_pass_kernel(
    const float* __restrict__ S, const int* __restrict__ cnt,
    const float* __restrict__ rmE, const float* __restrict__ riE,
    float* __restrict__ cmE, float* __restrict__ ciE,
    float* __restrict__ colsum_p)
{
  __shared__ float redm[1024], reds[1024], redp[1024];

  int b  = blockIdx.y;
  int j0 = blockIdx.x * 64;
  int nq_pad = (cnt[2 * b] + 63) & ~63;
  int nc_pad = (cnt[2 * b + 1] + 63) & ~63;
  if (j0 >= nc_pad) return;        // block-uniform exit before barriers
  int t  = threadIdx.x;

  int j     = j0 + (t & 63);
  int wv    = t >> 6;                        // 0..15
  int chunk = nq_pad >> 4;                   // rows per wave (mult of 4)
  int i0    = wv * chunk;
  const float* Sb  = S + ((size_t)b * SQ_ + i0) * SC_ + j;
  const float* rmb = rmE + b * SQ_ + i0;
  const float* rib = riE + b * SQ_ + i0;

  float cm = -INFINITY, cs = 0.f, cp = 0.f;
  for (int ii = 0; ii < chunk; ++ii) {
    float v = Sb[(size_t)ii * SC_];
    cp += __expf(v - rmb[ii]) * rib[ii];
    if (v > cm) { cs = cs * __expf(cm - v) + 1.0f; cm = v; }
    else if (cm > -INFINITY) cs += __expf(v - cm);
  }

  redm[t] = cm; reds[t] = cs; redp[t] = cp;
  __syncthreads();
  if (t < 64) {
    float m = redm[t], s = reds[t], p = redp[t];
#pragma unroll
    for (int wv2 = 1; wv2 < 16; ++wv2) {
      float om = redm[wv2 * 64 + t], os = reds[wv2 * 64 + t];
      float nm = fmaxf(m, om);
      float e1 = (m == nm) ? 1.f : __expf(m - nm);
      float e2 = (om == nm) ? 1.f : __expf(om - nm);
      s = s * e1 + os * e2; m = nm;
      p += redp[wv2 * 64 + t];
    }
    bool dead = !(s > 0.f);
    cmE[b * SC_ + j0 + t] = dead ? INFINITY : m;
    ciE[b * SC_ + j0 + t] = dead ? 0.f : 1.0f / s;
    colsum_p[b * SC_ + j0 + t] = p;
  }
}

// ---------------------------------------------------------------------------
// Kernel 4: rowsum_pp[b,i] = sum_j exp(S - cmE_j) * ciE_j. Pure streaming.
// ---------------------------------------------------------------------------
__global__ __launch_bounds__(256) void rowsum_pp_kernel(
    const float* __restrict__ S, const int* __restrict__ cnt,
    const float* __restrict__ cmE, const float* __restrict__ ciE,
    float* __restrict__ rowsum_pp)
{
  int t = threadIdx.x;
  int row0 = blockIdx.x * 4;        // 4 rows per block, same b
  int b = row0 >> 10;
  int nq = cnt[2 * b];
  if ((row0 & 1023) >= nq) return;
  int nc_pad = (cnt[2 * b + 1] + 63) & ~63;

  int w = t >> 6, lane = t & 63;
  int row = row0 + w;
  const float4* Sr  = (const float4*)(S + (size_t)row * SC_);
  const float4* cm4 = (const float4*)(cmE + b * SC_);
  const float4* ci4 = (const float4*)(ciE + b * SC_);

  float accv = 0.f;
  int n4 = nc_pad >> 2;             // float4 count (multiple of 16)
  for (int j4 = lane; j4 < n4; j4 += 64) {
    float4 v = Sr[j4];
    float4 cm = cm4[j4];
    float4 ci = ci4[j4];
    accv += __expf(v.x - cm.x) * ci.x;
    accv += __expf(v.y - cm.y) * ci.y;
    accv += __expf(v.z - cm.z) * ci.z;
    accv += __expf(v.w - cm.w) * ci.w;
  }
#pragma unroll
  for (int o = 32; o; o >>= 1) accv += __shfl_xor(accv, o);
  if (lane == 0) rowsum_pp[row] = accv;
}

// ---------------------------------------------------------------------------
// Kernel 5: combine partials over VALID rows via idx gather. 32 j-chunks.
// ---------------------------------------------------------------------------
__global__ __launch_bounds__(256) void combine_kernel(
    const float* __restrict__ q, const float* __restrict__ c,
    const int* __restrict__ idx_q, const int* __restrict__ idx_c,
    const int* __restrict__ cnt,
    const float* __restrict__ colsum_p, const float* __restrict__ rowsum_pp,
    float* __restrict__ Xp)
{
  int jc = blockIdx.x;   // 0..31
  int op = blockIdx.y;   // 0: c/colsum_p ; 1: q/rowsum_pp
  int b  = blockIdx.z;
  int t  = threadIdx.x;

  int n = op ? cnt[2 * b] : cnt[2 * b + 1];
  const float* src = op ? (q + (size_t)b * SQ_ * D_) : (c + (size_t)b * SC_ * D_);
  const float* wv  = op ? (rowsum_pp + b * SQ_) : (colsum_p + b * SC_);
  const int*   idx = (op ? idx_q : idx_c) + b * 1024;

  float a0 = 0.f, a1 = 0.f, a2 = 0.f;
  int je = min(jc * 32 + 32, n);
  for (int j = jc * 32; j < je; ++j) {
    float wj = wv[j];
    const float* r = src + (size_t)idx[j] * D_;
    a0 += wj * r[t];
    a1 += wj * r[t + 256];
    a2 += wj * r[t + 512];
  }
  float* xp = Xp + ((size_t)jc * B_ + b) * H_ + op * D_;
  xp[t] = a0; xp[t + 256] = a1; xp[t + 512] = a2;
}

// ---------------------------------------------------------------------------
// Kernel 6: reduce Xp over 32 chunks -> X[b][1536]
// ---------------------------------------------------------------------------
__global__ __launch_bounds__(256) void reduce_x_kernel(
    const float* __restrict__ Xp, float* __restrict__ X)
{
  int idx = blockIdx.x * 256 + threadIdx.x;
  float s = 0.f;
#pragma unroll
  for (int ch = 0; ch < 32; ++ch) s += Xp[(size_t)ch * B_ * H_ + idx];
  X[idx] = s;
}

// ---------------------------------------------------------------------------
// Kernel 7: fc1. One wave per h; W1 row held in registers, loop over the
// 16 batches -> W1 read exactly once from HBM (9.4 MB, was ~150 MB).
// ---------------------------------------------------------------------------
__global__ __launch_bounds__(256) void fc1_kernel(
    const float* __restrict__ X, const float* __restrict__ W1,
    const float* __restrict__ b1, float* __restrict__ Y)
{
  int w = threadIdx.x >> 6, lane = threadIdx.x & 63;
  int h = blockIdx.x * 4 + w;           // 0..1535
  const float4* wr = (const float4*)(W1 + (size_t)h * H_);
  float4 wv[6];
#pragma unroll
  for (int it = 0; it < 6; ++it) wv[it] = wr[it * 64 + lane];
  float bias = b1[h];

  for (int b = 0; b < B_; ++b) {
    const float4* x = (const float4*)(X + (size_t)b * H_);
    float accv = 0.f;
#pragma unroll
    for (int it = 0; it < 6; ++it) {
      float4 xv = x[it * 64 + lane];
      accv += xv.x * wv[it].x + xv.y * wv[it].y + xv.z * wv[it].z + xv.w * wv[it].w;
    }
#pragma unroll
    for (int o = 32; o; o >>= 1) accv += __shfl_xor(accv, o);
    if (lane == 0) Y[(size_t)b * H_ + h] = tanhf(accv + bias);
  }
}

// ---------------------------------------------------------------------------
// Kernel 8: fc2 + log_softmax + NLL loss.
// ---------------------------------------------------------------------------
__global__ __launch_bounds__(64) void fc2_loss_kernel(
    const float* __restrict__ Y, const float* __restrict__ W2,
    const float* __restrict__ b2, const int* __restrict__ labels,
    float* __restrict__ out)
{
  __shared__ float logp_s[B_][2];
  int t = threadIdx.x;
  if (t < 2 * B_) {
    int b = t >> 1, n = t & 1;
    const float* y = Y + (size_t)b * H_;
    const float* w = W2 + (size_t)n * H_;
    float accv = b2[n];
    for (int k = 0; k < H_; ++k) accv += y[k] * w[k];
    logp_s[b][n] = accv;
  }
  __syncthreads();
  if (t < B_) {
    float l0 = logp_s[t][0], l1 = logp_s[t][1];
    float m = fmaxf(l0, l1);
    float lse = m + logf(expf(l0 - m) + expf(l1 - m));
    logp_s[t][0] = l0 - lse;
    logp_s[t][1] = l1 - lse;
  }
  __syncthreads();
  if (t < 2 * B_) out[1 + t] = logp_s[t >> 1][t & 1];
  if (t == 0) {
    float loss = 0.f;
    for (int b = 0; b < B_; ++b) loss -= logp_s[b][labels[b]];
    out[0] = loss / (float)B_;
  }
}

// ---------------------------------------------------------------------------
extern "C" void kernel_launch(void* const* d_in, const int* in_sizes, int n_in,
                              void* d_out, int out_size, void* d_ws, size_t ws_size,
                              hipStream_t stream) {
  const float* q      = (const float*)d_in[0];
  const float* c      = (const float*)d_in[1];
  const int*   mask_q = (const int*)d_in[2];
  const int*   mask_c = (const int*)d_in[3];
  const int*   labels = (const int*)d_in[4];
  const float* W1     = (const float*)d_in[5];
  const float* b1     = (const float*)d_in[6];
  const float* W2     = (const float*)d_in[7];
  const float* b2     = (const float*)d_in[8];
  float* out = (float*)d_out;

  float* ws        = (float*)d_ws;
  float* S         = ws;                           // 16M floats (64 MiB)
  float* rmE       = ws + (size_t)B_ * SQ_ * SC_;
  float* riE       = rmE + B_ * SQ_;
  float* cmE       = riE + B_ * SQ_;
  float* ciE       = cmE + B_ * SC_;
  float* colsum_p  = ciE + B_ * SC_;
  float* rowsum_pp = colsum_p + B_ * SC_;
  int*   cnt       = (int*)(rowsum_pp + B_ * SQ_);
  int*   idx_q     = cnt + 2 * B_;
  int*   idx_c     = idx_q + B_ * SQ_;
  // After rowsum_pp, S is dead: reuse its space for Xp / X / Y.
  float* Xp        = ws;                           // 32*16*1536 floats (3 MiB)
  float* X         = ws + 32 * B_ * H_;
  float* Y         = X + B_ * H_;

  compact_kernel<<<2 * B_, 256, 0, stream>>>(mask_q, mask_c, idx_q, idx_c, cnt);

  dim3 g1(SC_ / 64, SQ_ / 64, B_);
  gemm_mfma_kernel<<<g1, 256, 0, stream>>>(q, c, idx_q, idx_c, cnt, S);

  row_stats_kernel<<<(B_ * SQ_) / 4, 256, 0, stream>>>(S, cnt, rmE, riE);
  col_pass_kernel<<<dim3(SC_ / 64, B_), 1024, 0, stream>>>(S, cnt, rmE, riE,
                                                           cmE, ciE, colsum_p);
  rowsum_pp_kernel<<<(B_ * SQ_) / 4, 256, 0, stream>>>(S, cnt, cmE, ciE, rowsum_pp);

  combine_kernel<<<dim3(32, 2, B_), 256, 0, stream>>>(q, c, idx_q, idx_c, cnt,
                                                      colsum_p, rowsum_pp, Xp);
  reduce_x_kernel<<<(B_ * H_) / 256, 256, 0, stream>>>(Xp, X);
  fc1_kernel<<<H_ / 4, 256, 0, stream>>>(X, W1, b1, Y);
  fc2_loss_kernel<<<1, 64, 0, stream>>>(Y, W2, b2, labels, out);
}